// Round 1
// baseline (6358.723 us; speedup 1.0000x reference)
//
#include <hip/hip_runtime.h>
#include <hip/hip_bf16.h>
#include <math.h>

#define S 2048
#define HID 2048
#define NH 16
#define QL 1536
#define KVL 512
#define DN 128
#define DR 64
#define DV 128
#define DQ 192
#define IH 4
#define ID 128
#define TOPK 1024

// ---------------- generic SGEMM: C[M,N] = A[M,K] @ B[K,N], row-major fp32 ----
#define BM 128
#define BN 128
#define BK 16

__global__ __launch_bounds__(256) void sgemm_kernel(const float* __restrict__ A,
                                                    const float* __restrict__ B,
                                                    float* __restrict__ C,
                                                    int M, int N, int K) {
    __shared__ float As[BK][BM + 4];
    __shared__ float Bs[BK][BN + 4];
    int tid = threadIdx.x;
    int row0 = blockIdx.y * BM, col0 = blockIdx.x * BN;
    int tr = tid >> 4, tc = tid & 15;
    float acc[8][8];
#pragma unroll
    for (int i = 0; i < 8; i++)
#pragma unroll
        for (int j = 0; j < 8; j++) acc[i][j] = 0.f;

    for (int k0 = 0; k0 < K; k0 += BK) {
        // Load A tile (128 x 16), transposed into As[k][m]. K is a multiple of 16 here.
#pragma unroll
        for (int i = 0; i < 2; i++) {
            int v = tid + i * 256;          // 0..511 float4 slots
            int m = v >> 2;                 // 0..127
            int kq = (v & 3) * 4;           // 0,4,8,12
            int gr = row0 + m;
            float4 a;
            if (gr < M) a = *(const float4*)(A + (size_t)gr * K + (k0 + kq));
            else a = make_float4(0.f, 0.f, 0.f, 0.f);
            As[kq + 0][m] = a.x; As[kq + 1][m] = a.y;
            As[kq + 2][m] = a.z; As[kq + 3][m] = a.w;
        }
        // Load B tile (16 x 128)
#pragma unroll
        for (int i = 0; i < 2; i++) {
            int v = tid + i * 256;
            int kk = v >> 5;                // 0..15
            int nq = (v & 31) * 4;          // 0..124
            int gc = col0 + nq;
            const float* Bp = B + (size_t)(k0 + kk) * N + gc;
            float4 b;
            if (gc + 3 < N) {
                b = *(const float4*)Bp;
            } else {
                b.x = (gc + 0 < N) ? Bp[0] : 0.f;
                b.y = (gc + 1 < N) ? Bp[1] : 0.f;
                b.z = (gc + 2 < N) ? Bp[2] : 0.f;
                b.w = (gc + 3 < N) ? Bp[3] : 0.f;
            }
            Bs[kk][nq + 0] = b.x; Bs[kk][nq + 1] = b.y;
            Bs[kk][nq + 2] = b.z; Bs[kk][nq + 3] = b.w;
        }
        __syncthreads();
#pragma unroll
        for (int kk = 0; kk < BK; kk++) {
            float a[8], b[8];
#pragma unroll
            for (int i = 0; i < 8; i++) a[i] = As[kk][tr * 8 + i];
#pragma unroll
            for (int i = 0; i < 8; i++) b[i] = Bs[kk][tc * 8 + i];
#pragma unroll
            for (int i = 0; i < 8; i++)
#pragma unroll
                for (int j = 0; j < 8; j++) acc[i][j] += a[i] * b[j];
        }
        __syncthreads();
    }
#pragma unroll
    for (int i = 0; i < 8; i++) {
        int gr = row0 + tr * 8 + i;
        if (gr >= M) continue;
#pragma unroll
        for (int j = 0; j < 8; j++) {
            int gc = col0 + tc * 8 + j;
            if (gc < N) C[(size_t)gr * N + gc] = acc[i][j];
        }
    }
}

// ---------------- rmsnorm (strided in/out), 256 threads/row ----------------
__global__ __launch_bounds__(256) void rmsnorm_kernel(const float* __restrict__ in, int istride,
                                                      float* __restrict__ out, int ostride,
                                                      const float* __restrict__ w, int L) {
    int row = blockIdx.x, tid = threadIdx.x;
    const float* xr = in + (size_t)row * istride;
    float* yr = out + (size_t)row * ostride;
    __shared__ float red[256];
    float ss = 0.f;
    for (int i = tid; i < L; i += 256) { float v = xr[i]; ss += v * v; }
    red[tid] = ss; __syncthreads();
    for (int st = 128; st > 0; st >>= 1) {
        if (tid < st) red[tid] += red[tid + st];
        __syncthreads();
    }
    float scale = rsqrtf(red[0] / (float)L + 1e-6f);
    for (int i = tid; i < L; i += 256) yr[i] = xr[i] * scale * w[i];
}

// ---------------- RoPE interleaved on q_pe (q: [S, NH, 192], pe at 128..191) --
__global__ void rope_q_kernel(float* __restrict__ q, const float* __restrict__ cosb,
                              const float* __restrict__ sinb) {
    int idx = blockIdx.x * 256 + threadIdx.x;     // S*NH*32
    int j = idx & 31, h = (idx >> 5) & 15, t = idx >> 9;
    float c = cosb[t * 32 + j], s = sinb[t * 32 + j];
    float* p = q + ((size_t)t * NH + h) * DQ + DN + 2 * j;
    float xr = p[0], xi = p[1];
    p[0] = xr * c - xi * s;
    p[1] = xr * s + xi * c;
}

// ---------------- RoPE interleaved k_pe: kvf[:,512:576] -> kpe[S,64] ---------
__global__ void rope_kpe_kernel(const float* __restrict__ kvf, float* __restrict__ kpe,
                                const float* __restrict__ cosb, const float* __restrict__ sinb) {
    int idx = blockIdx.x * 256 + threadIdx.x;     // S*32
    int j = idx & 31, t = idx >> 5;
    float c = cosb[t * 32 + j], s = sinb[t * 32 + j];
    const float* p = kvf + (size_t)t * (KVL + DR) + KVL + 2 * j;
    float xr = p[0], xi = p[1];
    kpe[t * 64 + 2 * j] = xr * c - xi * s;
    kpe[t * 64 + 2 * j + 1] = xr * s + xi * c;
}

// ---------------- RoPE non-interleaved on qi first 64 dims (qi: [S,4,128]) ---
__global__ void rope_qi_kernel(float* __restrict__ qi, const float* __restrict__ cosb,
                               const float* __restrict__ sinb) {
    int idx = blockIdx.x * 256 + threadIdx.x;     // S*4*32
    int j = idx & 31, h = (idx >> 5) & 3, t = idx >> 7;
    float c = cosb[t * 32 + j], s = sinb[t * 32 + j];
    float* p = qi + ((size_t)t * IH + h) * ID;
    float x1 = p[j], x2 = p[j + 32];
    p[j] = x1 * c - x2 * s;
    p[j + 32] = x1 * s + x2 * c;
}

// ---------------- layernorm + RoPE(non-interleaved, first 64) on ki rows -----
__global__ __launch_bounds__(128) void ki_ln_rope_kernel(float* __restrict__ ki,
                                                         const float* __restrict__ g,
                                                         const float* __restrict__ bb,
                                                         const float* __restrict__ cosb,
                                                         const float* __restrict__ sinb) {
    int t = blockIdx.x, tid = threadIdx.x;  // 128 threads
    float* p = ki + (size_t)t * ID;
    __shared__ float s1[128], s2m[128];
    float v = p[tid];
    s1[tid] = v; s2m[tid] = v * v; __syncthreads();
    for (int st = 64; st > 0; st >>= 1) {
        if (tid < st) { s1[tid] += s1[tid + st]; s2m[tid] += s2m[tid + st]; }
        __syncthreads();
    }
    float mu = s1[0] / 128.f;
    float var = s2m[0] / 128.f - mu * mu;
    float y = (v - mu) * rsqrtf(var + 1e-6f) * g[tid] + bb[tid];
    __syncthreads();
    s1[tid] = y; __syncthreads();
    if (tid >= 64) {
        p[tid] = y;
    } else if (tid < 32) {
        float c = cosb[t * 32 + tid], s = sinb[t * 32 + tid];
        float x1 = s1[tid], x2 = s1[tid + 32];
        p[tid] = x1 * c - x2 * s;
        p[tid + 32] = x1 * s + x2 * c;
    }
}

// ---------------- transpose ki [S,128] -> kiT [128,S] ------------------------
__global__ void transpose_ki_kernel(const float* __restrict__ ki, float* __restrict__ kiT) {
    int idx = blockIdx.x * 256 + threadIdx.x;   // S*128
    int t = idx >> 7, d = idx & 127;
    kiT[(size_t)d * S + t] = ki[idx];
}

// ---------------- indexer score: iscore[t][s] for s<=t -----------------------
__global__ __launch_bounds__(256) void iscore_kernel(const float* __restrict__ qi,
                                                     const float* __restrict__ kiT,
                                                     const float* __restrict__ iw,
                                                     float* __restrict__ iscore) {
    int t = blockIdx.x;
    if ((int)(blockIdx.y * 256) > t) return;  // uniform early-out
    int s = blockIdx.y * 256 + threadIdx.x;
    __shared__ float qs[4 * ID];
    __shared__ float ws[4];
    for (int i = threadIdx.x; i < 4 * ID; i += 256) qs[i] = qi[(size_t)t * (4 * ID) + i];
    if (threadIdx.x < 4) ws[threadIdx.x] = iw[t * 4 + threadIdx.x] * 0.04419417382415922f;
    __syncthreads();
    if (s > t) return;
    float a0 = 0.f, a1 = 0.f, a2 = 0.f, a3 = 0.f;
    for (int d = 0; d < ID; d++) {
        float kv = kiT[(size_t)d * S + s];
        a0 += qs[d] * kv;
        a1 += qs[ID + d] * kv;
        a2 += qs[2 * ID + d] * kv;
        a3 += qs[3 * ID + d] * kv;
    }
    float sc = fmaxf(a0, 0.f) * ws[0] + fmaxf(a1, 0.f) * ws[1] +
               fmaxf(a2, 0.f) * ws[2] + fmaxf(a3, 0.f) * ws[3];
    iscore[(size_t)t * S + s] = sc;
}

// ---------------- exact top-k (radix select + jax tie-break) -----------------
__device__ inline unsigned sortable_u32(float f) {
    unsigned u = __float_as_uint(f);
    return (u & 0x80000000u) ? ~u : (u | 0x80000000u);
}

__global__ __launch_bounds__(256) void topk_kernel(const float* __restrict__ iscore,
                                                   int* __restrict__ selidx,
                                                   int* __restrict__ selcnt) {
    int t = blockIdx.x, tid = threadIdx.x;
    int* outIdx = selidx + (size_t)t * TOPK;
    if (t < TOPK) {   // all causal keys kept
        for (int j = tid; j <= t; j += 256) outIdx[j] = j;
        if (tid == 0) selcnt[t] = t + 1;
        return;
    }
    const float* row = iscore + (size_t)t * S;
    int n = t + 1;
    __shared__ int hist[256];
    __shared__ int scan_res[2];
    unsigned prefix = 0, prefmask = 0;
    int k = TOPK;           // remaining rank
    for (int pass = 0; pass < 4; pass++) {
        int shift = 24 - pass * 8;
        hist[tid] = 0; __syncthreads();
        for (int j = tid; j < n; j += 256) {
            unsigned u = sortable_u32(row[j]);
            if ((u & prefmask) == prefix) atomicAdd(&hist[(u >> shift) & 255], 1);
        }
        __syncthreads();
        if (tid == 0) {
            int cum = 0, b = 255;
            for (; b > 0; b--) {
                if (cum + hist[b] >= k) break;
                cum += hist[b];
            }
            scan_res[0] = b; scan_res[1] = cum;
        }
        __syncthreads();
        int b = scan_res[0], cum = scan_res[1];
        k -= cum;
        prefix |= ((unsigned)b) << shift;
        prefmask |= (0xFFu << shift);
        __syncthreads();
    }
    unsigned u_thr = prefix;   // exact k-th largest key; k = #equals to take
    __shared__ int cnt;
    if (tid == 0) cnt = 0;
    __syncthreads();
    for (int j = tid; j < n; j += 256) {
        unsigned u = sortable_u32(row[j]);
        if (u > u_thr) { int p = atomicAdd(&cnt, 1); outIdx[p] = j; }
    }
    __syncthreads();
    int base = cnt;
    int need = TOPK - base;   // take equals lowest-index-first (jax tie-break)
    __shared__ int eqflags[256];
    __shared__ int taken;
    if (tid == 0) taken = 0;
    __syncthreads();
    for (int j0 = 0; j0 < n && taken < need; j0 += 256) {
        int j = j0 + tid;
        int f = 0;
        if (j < n) f = (sortable_u32(row[j]) == u_thr);
        eqflags[tid] = f; __syncthreads();
        if (tid == 0) {
            int tk = taken;
            for (int i = 0; i < 256 && tk < need; i++)
                if (eqflags[i]) { outIdx[base + tk] = j0 + i; tk++; }
            taken = tk;
        }
        __syncthreads();
    }
    if (tid == 0) selcnt[t] = TOPK;
}

// ---------------- sparse attention over selected keys ------------------------
__global__ __launch_bounds__(256) void attn_kernel(const float* __restrict__ q,
                                                   const float* __restrict__ kvexp,
                                                   const float* __restrict__ kpe,
                                                   const int* __restrict__ selidx,
                                                   const int* __restrict__ selcnt,
                                                   float* __restrict__ attn_out) {
    int t = blockIdx.x, h = blockIdx.y, tid = threadIdx.x;
    int n = selcnt[t];
    const int* idxs = selidx + (size_t)t * TOPK;
    __shared__ float qs[DQ];
    __shared__ float sc[TOPK];
    __shared__ float red[256];
    const float* qrow = q + ((size_t)t * NH + h) * DQ;
    for (int i = tid; i < DQ; i += 256) qs[i] = qrow[i];
    __syncthreads();
    const float scale = 0.07216878364870322f;  // 192^-0.5
    float lmax = -1e30f;
    for (int j = tid; j < n; j += 256) {
        int key = idxs[j];
        const float* kn = kvexp + ((size_t)key * NH + h) * (DN + DV);
        const float* kp = kpe + (size_t)key * DR;
        float acc = 0.f;
#pragma unroll
        for (int d = 0; d < DN; d += 4) {
            float4 k4 = *(const float4*)(kn + d);
            acc += qs[d] * k4.x + qs[d + 1] * k4.y + qs[d + 2] * k4.z + qs[d + 3] * k4.w;
        }
#pragma unroll
        for (int d = 0; d < DR; d += 4) {
            float4 k4 = *(const float4*)(kp + d);
            acc += qs[DN + d] * k4.x + qs[DN + d + 1] * k4.y +
                   qs[DN + d + 2] * k4.z + qs[DN + d + 3] * k4.w;
        }
        acc *= scale;
        sc[j] = acc;
        lmax = fmaxf(lmax, acc);
    }
    red[tid] = lmax; __syncthreads();
    for (int st = 128; st > 0; st >>= 1) {
        if (tid < st) red[tid] = fmaxf(red[tid], red[tid + st]);
        __syncthreads();
    }
    float m = red[0]; __syncthreads();
    float lsum = 0.f;
    for (int j = tid; j < n; j += 256) {
        float e = __expf(sc[j] - m);
        sc[j] = e; lsum += e;
    }
    red[tid] = lsum; __syncthreads();
    for (int st = 128; st > 0; st >>= 1) {
        if (tid < st) red[tid] += red[tid + st];
        __syncthreads();
    }
    float inv = 1.0f / red[0];
    __syncthreads();
    if (tid < DV) {   // thread d accumulates output dim d; v-reads coalesced
        int d = tid;
        float acc = 0.f;
        for (int j = 0; j < n; j++) {
            int key = idxs[j];
            acc += sc[j] * kvexp[((size_t)key * NH + h) * (DN + DV) + DN + d];
        }
        attn_out[(size_t)t * (NH * DV) + h * DV + d] = acc * inv;
    }
}

// ---------------- host ------------------------------------------------------
static inline void launch_sgemm(const float* A, const float* B, float* C,
                                int M, int N, int K, hipStream_t s) {
    dim3 grid((N + BN - 1) / BN, (M + BM - 1) / BM);
    sgemm_kernel<<<grid, 256, 0, s>>>(A, B, C, M, N, K);
}

extern "C" void kernel_launch(void* const* d_in, const int* in_sizes, int n_in,
                              void* d_out, int out_size, void* d_ws, size_t ws_size,
                              hipStream_t stream) {
    const float* x        = (const float*)d_in[0];
    const float* cosb     = (const float*)d_in[1];
    const float* sinb     = (const float*)d_in[2];
    // d_in[3] = mask (causality handled directly)
    const float* Wq_a     = (const float*)d_in[4];
    const float* q_norm_w = (const float*)d_in[5];
    const float* Wq_b     = (const float*)d_in[6];
    const float* Wkv_a    = (const float*)d_in[7];
    const float* kv_norm_w= (const float*)d_in[8];
    const float* Wkv_b    = (const float*)d_in[9];
    const float* Wo       = (const float*)d_in[10];
    const float* IWq_b    = (const float*)d_in[11];
    const float* IWk      = (const float*)d_in[12];
    const float* Ik_norm_w= (const float*)d_in[13];
    const float* Ik_norm_b= (const float*)d_in[14];
    const float* IWproj   = (const float*)d_in[15];
    float* out = (float*)d_out;

    float* ws = (float*)d_ws;
    size_t off = 0;
    float* qr     = ws + off; off += (size_t)S * QL;            // 2048x1536
    float* q      = ws + off; off += (size_t)S * NH * DQ;       // 2048x3072
    float* kvf    = ws + off; off += (size_t)S * (KVL + DR);    // 2048x576
    float* kvn    = ws + off; off += (size_t)S * KVL;           // 2048x512
    float* kpe    = ws + off; off += (size_t)S * DR;            // 2048x64
    float* kvexp  = ws + off; off += (size_t)S * NH * (DN + DV);// 2048x4096
    float* qi     = ws + off; off += (size_t)S * IH * ID;       // 2048x512
    float* ki     = ws + off; off += (size_t)S * ID;            // 2048x128
    float* kiT    = ws + off; off += (size_t)S * ID;            // 128x2048
    float* iw     = ws + off; off += (size_t)S * IH;            // 2048x4
    float* iscore = ws + off; off += (size_t)S * S;             // 2048x2048
    float* attn_o = ws + off; off += (size_t)S * NH * DV;       // 2048x2048
    int* selidx   = (int*)(ws + off); off += (size_t)S * TOPK;  // 2048x1024
    int* selcnt   = (int*)(ws + off); off += S;

    // 1) qr = rmsnorm(x @ Wq_a)
    launch_sgemm(x, Wq_a, qr, S, QL, HID, stream);
    rmsnorm_kernel<<<S, 256, 0, stream>>>(qr, QL, qr, QL, q_norm_w, QL);
    // 2) q = qr @ Wq_b ; rope q_pe (interleaved)
    launch_sgemm(qr, Wq_b, q, S, NH * DQ, QL, stream);
    rope_q_kernel<<<(S * NH * 32) / 256, 256, 0, stream>>>(q, cosb, sinb);
    // 3) kv_full = x @ Wkv_a ; split/norm/rope
    launch_sgemm(x, Wkv_a, kvf, S, KVL + DR, HID, stream);
    rmsnorm_kernel<<<S, 256, 0, stream>>>(kvf, KVL + DR, kvn, KVL, kv_norm_w, KVL);
    rope_kpe_kernel<<<(S * 32) / 256, 256, 0, stream>>>(kvf, kpe, cosb, sinb);
    // 4) kv_exp = kvn @ Wkv_b
    launch_sgemm(kvn, Wkv_b, kvexp, S, NH * (DN + DV), KVL, stream);
    // 5) indexer inputs
    launch_sgemm(qr, IWq_b, qi, S, IH * ID, QL, stream);
    rope_qi_kernel<<<(S * IH * 32) / 256, 256, 0, stream>>>(qi, cosb, sinb);
    launch_sgemm(x, IWk, ki, S, ID, HID, stream);
    ki_ln_rope_kernel<<<S, 128, 0, stream>>>(ki, Ik_norm_w, Ik_norm_b, cosb, sinb);
    launch_sgemm(x, IWproj, iw, S, IH, HID, stream);
    transpose_ki_kernel<<<(S * ID) / 256, 256, 0, stream>>>(ki, kiT);
    // 6) indexer scores (causal region only)
    {
        dim3 grid(S, (S + 255) / 256);
        iscore_kernel<<<grid, 256, 0, stream>>>(qi, kiT, iw, iscore);
    }
    // 7) exact top-k selection
    topk_kernel<<<S, 256, 0, stream>>>(iscore, selidx, selcnt);
    // 8) sparse attention
    {
        dim3 grid(S, NH);
        attn_kernel<<<grid, 256, 0, stream>>>(q, kvexp, kpe, selidx, selcnt, attn_o);
    }
    // 9) out = attn_o @ Wo
    launch_sgemm(attn_o, Wo, out, S, HID, NH * DV, stream);

    (void)in_sizes; (void)n_in; (void)out_size; (void)ws_size;
}

// Round 2
// 927.280 us; speedup vs baseline: 6.8574x; 6.8574x over previous
//
#include <hip/hip_runtime.h>
#include <math.h>
#include <stdint.h>

#define S 2048
#define HID 2048
#define NH 16
#define QL 1536
#define KVL 512
#define DN 128
#define DR 64
#define DV 128
#define DQ 192
#define IH 4
#define ID 128
#define TOPK 1024

#define CDIV(a,b) (((a)+(b)-1)/(b))

typedef float f32x4 __attribute__((ext_vector_type(4)));
typedef short bf16x8 __attribute__((ext_vector_type(8)));

__device__ __forceinline__ ushort f2b(float f) {
    uint32_t u = __float_as_uint(f);
    u += 0x7fffu + ((u >> 16) & 1u);
    return (ushort)(u >> 16);
}

// ============ bf16 MFMA GEMM: C[M,N]f32 = A[M,K]bf16 @ BT[N,K]bf16 ==========
// M must be a multiple of 128 (always 2048 here). N,K arbitrary mult of 32 for K.
__global__ __launch_bounds__(256) void gemm_bt(const ushort* __restrict__ A,
                                               const ushort* __restrict__ BT,
                                               float* __restrict__ C,
                                               int M, int N, int K) {
    __shared__ ushort As[128 * 40];   // row stride 40 elems (80B) -> 2-way banks
    __shared__ ushort Bs[128 * 40];
    const int tid = threadIdx.x;
    const int w = tid >> 6, l = tid & 63;
    const int quad = l >> 4, lane = l & 15;
    const int row0 = blockIdx.y * 128, col0 = blockIdx.x * 128;
    const int wr = (w >> 1) * 64, wc = (w & 1) * 64;
    f32x4 acc[4][4];
#pragma unroll
    for (int i = 0; i < 4; i++)
#pragma unroll
        for (int j = 0; j < 4; j++) acc[i][j] = (f32x4)0.f;

    const int srow = tid >> 2, soff = tid & 3;
    const ushort* pa0 = A + (size_t)(row0 + srow) * K + soff * 8;
    const ushort* pa1 = pa0 + (size_t)64 * K;
    int bn0 = col0 + srow;      if (bn0 > N - 1) bn0 = N - 1;
    int bn1 = col0 + srow + 64; if (bn1 > N - 1) bn1 = N - 1;
    const ushort* pb0 = BT + (size_t)bn0 * K + soff * 8;
    const ushort* pb1 = BT + (size_t)bn1 * K + soff * 8;
    ushort* sa0 = As + srow * 40 + soff * 8;
    ushort* sa1 = As + (srow + 64) * 40 + soff * 8;
    ushort* sb0 = Bs + srow * 40 + soff * 8;
    ushort* sb1 = Bs + (srow + 64) * 40 + soff * 8;

    for (int k0 = 0; k0 < K; k0 += 32) {
        uint4 a0 = *(const uint4*)(pa0 + k0);
        uint4 a1 = *(const uint4*)(pa1 + k0);
        uint4 b0 = *(const uint4*)(pb0 + k0);
        uint4 b1 = *(const uint4*)(pb1 + k0);
        __syncthreads();
        *(uint4*)sa0 = a0; *(uint4*)sa1 = a1;
        *(uint4*)sb0 = b0; *(uint4*)sb1 = b1;
        __syncthreads();
        bf16x8 af[4], bf[4];
#pragma unroll
        for (int mi = 0; mi < 4; mi++)
            af[mi] = *(const bf16x8*)(As + (wr + mi * 16 + lane) * 40 + quad * 8);
#pragma unroll
        for (int ni = 0; ni < 4; ni++)
            bf[ni] = *(const bf16x8*)(Bs + (wc + ni * 16 + lane) * 40 + quad * 8);
#pragma unroll
        for (int mi = 0; mi < 4; mi++)
#pragma unroll
            for (int ni = 0; ni < 4; ni++)
                acc[mi][ni] = __builtin_amdgcn_mfma_f32_16x16x32_bf16(af[mi], bf[ni], acc[mi][ni], 0, 0, 0);
    }
#pragma unroll
    for (int mi = 0; mi < 4; mi++)
#pragma unroll
        for (int ni = 0; ni < 4; ni++)
#pragma unroll
            for (int r = 0; r < 4; r++) {
                int row = row0 + wr + mi * 16 + quad * 4 + r;
                int col = col0 + wc + ni * 16 + lane;
                if (col < N) C[(size_t)row * N + col] = acc[mi][ni][r];
            }
}

// ============ weight transpose+convert: W[K,N]f32 -> WT[N,K]bf16 =============
__global__ __launch_bounds__(256) void wtrans(const float* __restrict__ W, ushort* __restrict__ WT,
                                              int K, int N) {
    __shared__ float t[64][65];
    int k0 = blockIdx.x * 64, n0 = blockIdx.y * 64;
    int rr = threadIdx.x >> 6, cc = threadIdx.x & 63;
#pragma unroll
    for (int p = 0; p < 16; p++) {
        int k = k0 + p * 4 + rr, n = n0 + cc;
        t[p * 4 + rr][cc] = (k < K && n < N) ? W[(size_t)k * N + n] : 0.f;
    }
    __syncthreads();
#pragma unroll
    for (int p = 0; p < 16; p++) {
        int n = n0 + p * 4 + rr, k = k0 + cc;
        if (n < N && k < K) WT[(size_t)n * K + k] = f2b(t[cc][p * 4 + rr]);
    }
}

// ============ elementwise f32 -> bf16 (n mult of 1024) =======================
__global__ void cvt_bf16(const float* __restrict__ in, ushort* __restrict__ out) {
    int i = blockIdx.x * 256 + threadIdx.x;
    float4 v = *(const float4*)(in + (size_t)i * 4);
    uint32_t lo = (uint32_t)f2b(v.x) | ((uint32_t)f2b(v.y) << 16);
    uint32_t hi = (uint32_t)f2b(v.z) | ((uint32_t)f2b(v.w) << 16);
    *(uint2*)(out + (size_t)i * 4) = make_uint2(lo, hi);
}

// ============ rmsnorm f32 in -> bf16 out =====================================
__global__ __launch_bounds__(256) void rmsnorm_b(const float* __restrict__ in, int istride,
                                                 ushort* __restrict__ out, int ostride,
                                                 const float* __restrict__ w, int L) {
    int row = blockIdx.x, tid = threadIdx.x;
    const float* xr = in + (size_t)row * istride;
    ushort* yr = out + (size_t)row * ostride;
    __shared__ float red[256];
    float ss = 0.f;
    for (int i = tid; i < L; i += 256) { float v = xr[i]; ss += v * v; }
    red[tid] = ss; __syncthreads();
    for (int st = 128; st > 0; st >>= 1) {
        if (tid < st) red[tid] += red[tid + st];
        __syncthreads();
    }
    float scale = rsqrtf(red[0] / (float)L + 1e-6f);
    for (int i = tid; i < L; i += 256) yr[i] = f2b(xr[i] * scale * w[i]);
}

// ============ rope q (interleaved on dims 128..191) + scale -> qb[NH][S][192] bf16
__global__ void rope_q_b(const float* __restrict__ qf, ushort* __restrict__ qb,
                         const float* __restrict__ cosb, const float* __restrict__ sinb) {
    int idx = blockIdx.x * 256 + threadIdx.x;  // S*NH*96
    int p = idx % 96, h = (idx / 96) & 15, t = idx / (96 * 16);
    const float sc = 0.07216878364870322f;  // 192^-0.5 folded into Q
    const float* src = qf + (size_t)t * 3072 + h * 192;
    ushort* dst = qb + ((size_t)h * S + t) * 192;
    if (p < 64) {
        dst[2 * p]     = f2b(src[2 * p] * sc);
        dst[2 * p + 1] = f2b(src[2 * p + 1] * sc);
    } else {
        int j = p - 64;
        float c = cosb[t * 32 + j], s = sinb[t * 32 + j];
        float xr = src[128 + 2 * j], xi = src[128 + 2 * j + 1];
        dst[128 + 2 * j]     = f2b((xr * c - xi * s) * sc);
        dst[128 + 2 * j + 1] = f2b((xr * s + xi * c) * sc);
    }
}

// ============ rope k_pe: kvf[:,512:576] -> kpe[S,64] f32 =====================
__global__ void rope_kpe_kernel(const float* __restrict__ kvf, float* __restrict__ kpe,
                                const float* __restrict__ cosb, const float* __restrict__ sinb) {
    int idx = blockIdx.x * 256 + threadIdx.x;  // S*32
    int j = idx & 31, t = idx >> 5;
    float c = cosb[t * 32 + j], s = sinb[t * 32 + j];
    const float* p = kvf + (size_t)t * (KVL + DR) + KVL + 2 * j;
    float xr = p[0], xi = p[1];
    kpe[t * 64 + 2 * j] = xr * c - xi * s;
    kpe[t * 64 + 2 * j + 1] = xr * s + xi * c;
}

// ============ build kb[NH][S][192] bf16 from kvexp + kpe =====================
__global__ void build_kb(const float* __restrict__ kvexp, const float* __restrict__ kpe,
                         ushort* __restrict__ kb) {
    int idx = blockIdx.x * 256 + threadIdx.x;  // NH*S*192
    int d = idx % 192, s = (idx / 192) & 2047, h = idx / (192 * 2048);
    float v = (d < 128) ? kvexp[(size_t)s * 4096 + h * 256 + d] : kpe[s * 64 + (d - 128)];
    kb[idx] = f2b(v);
}

// ============ vT[NH][128][S] bf16 = transpose of kvexp V part ================
__global__ __launch_bounds__(256) void vtrans(const float* __restrict__ kvexp, ushort* __restrict__ vT) {
    __shared__ float t[64][65];
    int s0 = blockIdx.x * 64, d0 = blockIdx.y * 64, h = blockIdx.z;
    int rr = threadIdx.x >> 6, cc = threadIdx.x & 63;
#pragma unroll
    for (int p = 0; p < 16; p++)
        t[p * 4 + rr][cc] = kvexp[(size_t)(s0 + p * 4 + rr) * 4096 + h * 256 + 128 + d0 + cc];
    __syncthreads();
#pragma unroll
    for (int p = 0; p < 16; p++)
        vT[((size_t)h * 128 + d0 + p * 4 + rr) * S + s0 + cc] = f2b(t[cc][p * 4 + rr]);
}

// ============ rope non-interleaved on qi first 64 dims (qi: [S,4,128] f32) ===
__global__ void rope_qi_kernel(float* __restrict__ qi, const float* __restrict__ cosb,
                               const float* __restrict__ sinb) {
    int idx = blockIdx.x * 256 + threadIdx.x;  // S*4*32
    int j = idx & 31, h = (idx >> 5) & 3, t = idx >> 7;
    float c = cosb[t * 32 + j], s = sinb[t * 32 + j];
    float* p = qi + ((size_t)t * IH + h) * ID;
    float x1 = p[j], x2 = p[j + 32];
    p[j] = x1 * c - x2 * s;
    p[j + 32] = x1 * s + x2 * c;
}

// ============ layernorm + rope (non-interleaved, first 64) on ki rows ========
__global__ __launch_bounds__(128) void ki_ln_rope_kernel(float* __restrict__ ki,
                                                         const float* __restrict__ g,
                                                         const float* __restrict__ bb,
                                                         const float* __restrict__ cosb,
                                                         const float* __restrict__ sinb) {
    int t = blockIdx.x, tid = threadIdx.x;
    float* p = ki + (size_t)t * ID;
    __shared__ float s1[128], s2m[128];
    float v = p[tid];
    s1[tid] = v; s2m[tid] = v * v; __syncthreads();
    for (int st = 64; st > 0; st >>= 1) {
        if (tid < st) { s1[tid] += s1[tid + st]; s2m[tid] += s2m[tid + st]; }
        __syncthreads();
    }
    float mu = s1[0] / 128.f;
    float var = s2m[0] / 128.f - mu * mu;
    float y = (v - mu) * rsqrtf(var + 1e-6f) * g[tid] + bb[tid];
    __syncthreads();
    s1[tid] = y; __syncthreads();
    if (tid >= 64) {
        p[tid] = y;
    } else if (tid < 32) {
        float c = cosb[t * 32 + tid], s = sinb[t * 32 + tid];
        float x1 = s1[tid], x2 = s1[tid + 32];
        p[tid] = x1 * c - x2 * s;
        p[tid + 32] = x1 * s + x2 * c;
    }
}

// ============ transpose ki [S,128] -> kiT [128,S] ============================
__global__ void transpose_ki_kernel(const float* __restrict__ ki, float* __restrict__ kiT) {
    int idx = blockIdx.x * 256 + threadIdx.x;  // S*128
    int t = idx >> 7, d = idx & 127;
    kiT[(size_t)d * S + t] = ki[idx];
}

// ============ iw[t][j] = x[t] . IWproj[:,j] ==================================
__global__ __launch_bounds__(256) void iw_kernel(const float* __restrict__ x,
                                                 const float* __restrict__ IWproj,
                                                 float* __restrict__ iw) {
    int t = blockIdx.x, tid = threadIdx.x;
    __shared__ float red[256];
    float p0 = 0.f, p1 = 0.f, p2 = 0.f, p3 = 0.f;
    for (int k = tid; k < HID; k += 256) {
        float a = x[(size_t)t * HID + k];
        const float* wr = IWproj + k * 4;
        p0 += a * wr[0]; p1 += a * wr[1]; p2 += a * wr[2]; p3 += a * wr[3];
    }
#pragma unroll
    for (int j = 0; j < 4; j++) {
        float v = (j == 0) ? p0 : (j == 1) ? p1 : (j == 2) ? p2 : p3;
        red[tid] = v; __syncthreads();
        for (int st = 128; st > 0; st >>= 1) {
            if (tid < st) red[tid] += red[tid + st];
            __syncthreads();
        }
        if (tid == 0) iw[t * 4 + j] = red[0];
        __syncthreads();
    }
}

// ============ indexer score (fp32, causal region only) =======================
__global__ __launch_bounds__(256) void iscore_kernel(const float* __restrict__ qi,
                                                     const float* __restrict__ kiT,
                                                     const float* __restrict__ iw,
                                                     float* __restrict__ iscore) {
    int t = blockIdx.x;
    if ((int)(blockIdx.y * 256) > t) return;
    int s = blockIdx.y * 256 + threadIdx.x;
    __shared__ float qs[4 * ID];
    __shared__ float ws[4];
    for (int i = threadIdx.x; i < 4 * ID; i += 256) qs[i] = qi[(size_t)t * (4 * ID) + i];
    if (threadIdx.x < 4) ws[threadIdx.x] = iw[t * 4 + threadIdx.x] * 0.04419417382415922f;
    __syncthreads();
    if (s > t) return;
    float a0 = 0.f, a1 = 0.f, a2 = 0.f, a3 = 0.f;
    for (int d = 0; d < ID; d++) {
        float kv = kiT[(size_t)d * S + s];
        a0 += qs[d] * kv;
        a1 += qs[ID + d] * kv;
        a2 += qs[2 * ID + d] * kv;
        a3 += qs[3 * ID + d] * kv;
    }
    float sc = fmaxf(a0, 0.f) * ws[0] + fmaxf(a1, 0.f) * ws[1] +
               fmaxf(a2, 0.f) * ws[2] + fmaxf(a3, 0.f) * ws[3];
    iscore[(size_t)t * S + s] = sc;
}

// ============ exact top-k (radix select + jax lowest-index tie-break) ========
__device__ inline unsigned sortable_u32(float f) {
    unsigned u = __float_as_uint(f);
    return (u & 0x80000000u) ? ~u : (u | 0x80000000u);
}

__global__ __launch_bounds__(256) void topk_kernel(const float* __restrict__ iscore,
                                                   int* __restrict__ selidx,
                                                   int* __restrict__ selcnt) {
    int t = blockIdx.x, tid = threadIdx.x;
    int* outIdx = selidx + (size_t)t * TOPK;
    if (t < TOPK) {
        for (int j = tid; j <= t; j += 256) outIdx[j] = j;
        if (tid == 0) selcnt[t] = t + 1;
        return;
    }
    const float* row = iscore + (size_t)t * S;
    int n = t + 1;
    __shared__ int hist[256];
    __shared__ int scan_res[2];
    unsigned prefix = 0, prefmask = 0;
    int k = TOPK;
    for (int pass = 0; pass < 4; pass++) {
        int shift = 24 - pass * 8;
        hist[tid] = 0; __syncthreads();
        for (int j = tid; j < n; j += 256) {
            unsigned u = sortable_u32(row[j]);
            if ((u & prefmask) == prefix) atomicAdd(&hist[(u >> shift) & 255], 1);
        }
        __syncthreads();
        if (tid == 0) {
            int cum = 0, b = 255;
            for (; b > 0; b--) {
                if (cum + hist[b] >= k) break;
                cum += hist[b];
            }
            scan_res[0] = b; scan_res[1] = cum;
        }
        __syncthreads();
        int b = scan_res[0], cum = scan_res[1];
        k -= cum;
        prefix |= ((unsigned)b) << shift;
        prefmask |= (0xFFu << shift);
        __syncthreads();
    }
    unsigned u_thr = prefix;
    __shared__ int cnt;
    if (tid == 0) cnt = 0;
    __syncthreads();
    for (int j = tid; j < n; j += 256) {
        unsigned u = sortable_u32(row[j]);
        if (u > u_thr) { int p = atomicAdd(&cnt, 1); outIdx[p] = j; }
    }
    __syncthreads();
    int base = cnt;
    int need = TOPK - base;
    __shared__ int eqflags[256];
    __shared__ int taken;
    if (tid == 0) taken = 0;
    __syncthreads();
    for (int j0 = 0; j0 < n && taken < need; j0 += 256) {
        int j = j0 + tid;
        int f = 0;
        if (j < n) f = (sortable_u32(row[j]) == u_thr);
        eqflags[tid] = f; __syncthreads();
        if (tid == 0) {
            int tk = taken;
            for (int i = 0; i < 256 && tk < need; i++)
                if (eqflags[i]) { outIdx[base + tk] = j0 + i; tk++; }
            taken = tk;
        }
        __syncthreads();
    }
    if (tid == 0) selcnt[t] = TOPK;
}

// ============ selected-key bitmap: msk[t][0..63] u32 =========================
__global__ __launch_bounds__(256) void mask_build(const int* __restrict__ selidx,
                                                  const int* __restrict__ selcnt,
                                                  uint32_t* __restrict__ msk) {
    int t = blockIdx.x, tid = threadIdx.x;
    __shared__ uint32_t bm[64];
    if (tid < 64) bm[tid] = 0u;
    __syncthreads();
    int n = selcnt[t];
    for (int j = tid; j < n; j += 256) {
        int idx = selidx[(size_t)t * TOPK + j];
        atomicOr(&bm[idx >> 5], 1u << (idx & 31));
    }
    __syncthreads();
    if (tid < 64) msk[t * 64 + tid] = bm[tid];
}

// ============ dense-causal masked flash attention (bf16 MFMA) ================
// grid (S/64, NH), 256 threads. Q pre-scaled by 192^-0.5.
__global__ __launch_bounds__(256) void fattn(const ushort* __restrict__ qb,
                                             const ushort* __restrict__ kb,
                                             const ushort* __restrict__ vT,
                                             const uint32_t* __restrict__ msk,
                                             ushort* __restrict__ attn_b) {
    __shared__ ushort Ks[64 * 200];   // K tile [64][192] pad->200 (2-way banks)
    __shared__ ushort Vs[128 * 72];   // V^T tile [128][64] pad->72
    __shared__ float Sc[64 * 66];
    __shared__ ushort Pm[64 * 72];
    __shared__ float mrow[64], lrow[64], arow[64];
    __shared__ float red[256];
    const int tid = threadIdx.x;
    const int w = tid >> 6, l = tid & 63, quad = l >> 4, lane = l & 15;
    const int h = blockIdx.y, q0 = blockIdx.x * 64;

    bf16x8 qf[6];
    {
        const ushort* qp = qb + ((size_t)h * S + q0 + w * 16 + lane) * 192;
#pragma unroll
        for (int ks = 0; ks < 6; ks++) qf[ks] = *(const bf16x8*)(qp + ks * 32 + quad * 8);
    }
    f32x4 oacc[8];
#pragma unroll
    for (int i = 0; i < 8; i++) oacc[i] = (f32x4)0.f;
    if (tid < 64) { mrow[tid] = -1e30f; lrow[tid] = 0.f; }

    const int ktiles = blockIdx.x + 1;
    for (int kt = 0; kt < ktiles; kt++) {
        const int s0 = kt * 64;
        __syncthreads();  // prev-iter LDS reads complete / init visible
        {   // stage K tile: 64 rows x 384B
            const ushort* src = kb + ((size_t)h * S + s0 + (tid >> 2)) * 192;
            ushort* dst = Ks + (tid >> 2) * 200;
#pragma unroll
            for (int i = 0; i < 6; i++) {
                int c = (tid & 3) + 4 * i;
                *(uint4*)(dst + c * 8) = *(const uint4*)(src + c * 8);
            }
        }
        {   // stage V^T tile: 128 rows x 128B
            const ushort* src = vT + ((size_t)h * 128 + (tid >> 1)) * S + s0;
            ushort* dst = Vs + (tid >> 1) * 72;
#pragma unroll
            for (int i = 0; i < 4; i++) {
                int c = (tid & 1) + 2 * i;
                *(uint4*)(dst + c * 8) = *(const uint4*)(src + c * 8);
            }
        }
        __syncthreads();
        // QK^T: wave w owns q rows w*16..w*16+15, all 64 keys
#pragma unroll
        for (int kq = 0; kq < 4; kq++) {
            f32x4 sacc = (f32x4)0.f;
#pragma unroll
            for (int ks = 0; ks < 6; ks++) {
                bf16x8 bfr = *(const bf16x8*)(Ks + (kq * 16 + lane) * 200 + ks * 32 + quad * 8);
                sacc = __builtin_amdgcn_mfma_f32_16x16x32_bf16(qf[ks], bfr, sacc, 0, 0, 0);
            }
#pragma unroll
            for (int r = 0; r < 4; r++)
                Sc[(w * 16 + quad * 4 + r) * 66 + kq * 16 + lane] = sacc[r];
        }
        __syncthreads();
        // online softmax: 4 threads per row, 16 cols each
        {
            const int r = tid >> 2, g = tid & 3;
            const uint32_t mword = msk[(q0 + r) * 64 + ((s0 + g * 16) >> 5)];
            const int sh = (g & 1) * 16;
            float vals[16];
            float vmax = -1e30f;
#pragma unroll
            for (int i = 0; i < 16; i++) {
                float v = Sc[r * 66 + g * 16 + i];
                if (!((mword >> (sh + i)) & 1u)) v = -1e30f;
                vals[i] = v;
                vmax = fmaxf(vmax, v);
            }
            red[tid] = vmax;
            __syncthreads();
            float m_tile = fmaxf(fmaxf(red[r * 4 + 0], red[r * 4 + 1]),
                                 fmaxf(red[r * 4 + 2], red[r * 4 + 3]));
            float m_old = mrow[r];
            float m_new = fmaxf(m_old, m_tile);
            float psum = 0.f;
#pragma unroll
            for (int i = 0; i < 16; i++) {
                float e = (vals[i] < -1e29f) ? 0.f : __expf(vals[i] - m_new);
                psum += e;
                Pm[r * 72 + g * 16 + i] = f2b(e);
            }
            __syncthreads();
            red[tid] = psum;
            __syncthreads();
            if (g == 0) {
                float a = __expf(m_old - m_new);
                lrow[r] = lrow[r] * a + (red[r * 4] + red[r * 4 + 1] + red[r * 4 + 2] + red[r * 4 + 3]);
                mrow[r] = m_new;
                arow[r] = a;
            }
            __syncthreads();
        }
        // rescale O and PV
        {
            float al[4];
#pragma unroll
            for (int r = 0; r < 4; r++) al[r] = arow[w * 16 + quad * 4 + r];
            bf16x8 pfr[2];
#pragma unroll
            for (int k2 = 0; k2 < 2; k2++)
                pfr[k2] = *(const bf16x8*)(Pm + (w * 16 + lane) * 72 + k2 * 32 + quad * 8);
#pragma unroll
            for (int nt = 0; nt < 8; nt++) {
#pragma unroll
                for (int r = 0; r < 4; r++) oacc[nt][r] *= al[r];
#pragma unroll
                for (int k2 = 0; k2 < 2; k2++) {
                    bf16x8 vfr = *(const bf16x8*)(Vs + (nt * 16 + lane) * 72 + k2 * 32 + quad * 8);
                    oacc[nt] = __builtin_amdgcn_mfma_f32_16x16x32_bf16(pfr[k2], vfr, oacc[nt], 0, 0, 0);
                }
            }
        }
    }
    // epilogue -> attn_b [S][NH*128] bf16
    {
        float inv[4];
#pragma unroll
        for (int r = 0; r < 4; r++) inv[r] = 1.f / lrow[w * 16 + quad * 4 + r];
#pragma unroll
        for (int nt = 0; nt < 8; nt++)
#pragma unroll
            for (int r = 0; r < 4; r++) {
                int row = q0 + w * 16 + quad * 4 + r;
                attn_b[(size_t)row * 2048 + h * 128 + nt * 16 + lane] = f2b(oacc[nt][r] * inv[r]);
            }
    }
}

// ============ host ===========================================================
extern "C" void kernel_launch(void* const* d_in, const int* in_sizes, int n_in,
                              void* d_out, int out_size, void* d_ws, size_t ws_size,
                              hipStream_t stream) {
    const float* x        = (const float*)d_in[0];
    const float* cosb     = (const float*)d_in[1];
    const float* sinb     = (const float*)d_in[2];
    const float* Wq_a     = (const float*)d_in[4];
    const float* q_norm_w = (const float*)d_in[5];
    const float* Wq_b     = (const float*)d_in[6];
    const float* Wkv_a    = (const float*)d_in[7];
    const float* kv_norm_w= (const float*)d_in[8];
    const float* Wkv_b    = (const float*)d_in[9];
    const float* Wo       = (const float*)d_in[10];
    const float* IWq_b    = (const float*)d_in[11];
    const float* IWk      = (const float*)d_in[12];
    const float* Ik_norm_w= (const float*)d_in[13];
    const float* Ik_norm_b= (const float*)d_in[14];
    const float* IWproj   = (const float*)d_in[15];
    float* out = (float*)d_out;

    char* ws = (char*)d_ws;
    size_t o = 0;
    auto take = [&](size_t b) { char* p = ws + o; o += (b + 255) & ~(size_t)255; return p; };
    ushort* xb     = (ushort*)take((size_t)S * HID * 2);
    ushort* qrb    = (ushort*)take((size_t)S * QL * 2);
    ushort* qb     = (ushort*)take((size_t)NH * S * DQ * 2);
    ushort* kvnb   = (ushort*)take((size_t)S * KVL * 2);
    float*  kpe    = (float*)take((size_t)S * DR * 4);
    ushort* kb     = (ushort*)take((size_t)NH * S * DQ * 2);
    ushort* vT     = (ushort*)take((size_t)NH * DV * S * 2);
    float*  iw     = (float*)take((size_t)S * IH * 4);
    int*    selcnt = (int*)take((size_t)S * 4);
    uint32_t* msk  = (uint32_t*)take((size_t)S * 64 * 4);
    ushort* poolw  = (ushort*)take((size_t)3072 * 1536 * 2);       // largest WT
    char*   poola  = take((size_t)33554432);                       // f32 activation pool
    char*   poolb  = take((size_t)16777216 + (size_t)S * TOPK * 4);

    float* qr_f   = (float*)poola;             // [S][QL]
    float* qf_f   = (float*)poola;             // [S][3072]
    float* kvf_f  = (float*)poola;             // [S][576]
    float* kvexp  = (float*)poola;             // [S][4096]
    float* qi     = (float*)poola;             // [S][512]   (after kvexp dead)
    float* ki     = (float*)(poola + 4194304); // [S][128]
    float* kiT    = (float*)(poola + 5242880); // [128][S]
    float* iscore = (float*)poolb;             // [S][S]
    int*   selidx = (int*)(poolb + 16777216);  // [S][TOPK]
    ushort* attn_b = (ushort*)poolb;           // [S][2048] (after iscore dead)

    // --- x -> bf16
    cvt_bf16<<<(S * HID) / 1024, 256, 0, stream>>>(x, xb);

    // --- qr = rmsnorm(x @ Wq_a)
    wtrans<<<dim3(CDIV(HID, 64), CDIV(QL, 64)), 256, 0, stream>>>(Wq_a, poolw, HID, QL);
    gemm_bt<<<dim3(QL / 128, S / 128), 256, 0, stream>>>(xb, poolw, qr_f, S, QL, HID);
    rmsnorm_b<<<S, 256, 0, stream>>>(qr_f, QL, qrb, QL, q_norm_w, QL);

    // --- q = qr @ Wq_b ; rope+scale -> qb bf16 [NH][S][192]
    wtrans<<<dim3(CDIV(QL, 64), CDIV(NH * DQ, 64)), 256, 0, stream>>>(Wq_b, poolw, QL, NH * DQ);
    gemm_bt<<<dim3((NH * DQ) / 128, S / 128), 256, 0, stream>>>(qrb, poolw, qf_f, S, NH * DQ, QL);
    rope_q_b<<<(S * NH * 96) / 256, 256, 0, stream>>>(qf_f, qb, cosb, sinb);

    // --- kv_full = x @ Wkv_a ; norm + rope
    wtrans<<<dim3(CDIV(HID, 64), CDIV(KVL + DR, 64)), 256, 0, stream>>>(Wkv_a, poolw, HID, KVL + DR);
    gemm_bt<<<dim3(CDIV(KVL + DR, 128), S / 128), 256, 0, stream>>>(xb, poolw, kvf_f, S, KVL + DR, HID);
    rmsnorm_b<<<S, 256, 0, stream>>>(kvf_f, KVL + DR, kvnb, KVL, kv_norm_w, KVL);
    rope_kpe_kernel<<<(S * 32) / 256, 256, 0, stream>>>(kvf_f, kpe, cosb, sinb);

    // --- kv_exp = kvn @ Wkv_b ; build kb / vT
    wtrans<<<dim3(CDIV(KVL, 64), CDIV(NH * (DN + DV), 64)), 256, 0, stream>>>(Wkv_b, poolw, KVL, NH * (DN + DV));
    gemm_bt<<<dim3((NH * (DN + DV)) / 128, S / 128), 256, 0, stream>>>(kvnb, poolw, kvexp, S, NH * (DN + DV), KVL);
    build_kb<<<(NH * S * DQ) / 256, 256, 0, stream>>>(kvexp, kpe, kb);
    vtrans<<<dim3(S / 64, DV / 64, NH), 256, 0, stream>>>(kvexp, vT);

    // --- indexer inputs (fp32 precision-sensitive path)
    wtrans<<<dim3(CDIV(QL, 64), CDIV(IH * ID, 64)), 256, 0, stream>>>(IWq_b, poolw, QL, IH * ID);
    gemm_bt<<<dim3((IH * ID) / 128, S / 128), 256, 0, stream>>>(qrb, poolw, qi, S, IH * ID, QL);
    rope_qi_kernel<<<(S * IH * 32) / 256, 256, 0, stream>>>(qi, cosb, sinb);
    wtrans<<<dim3(CDIV(HID, 64), CDIV(ID, 64)), 256, 0, stream>>>(IWk, poolw, HID, ID);
    gemm_bt<<<dim3(ID / 128, S / 128), 256, 0, stream>>>(xb, poolw, ki, S, ID, HID);
    ki_ln_rope_kernel<<<S, 128, 0, stream>>>(ki, Ik_norm_w, Ik_norm_b, cosb, sinb);
    iw_kernel<<<S, 256, 0, stream>>>(x, IWproj, iw);
    transpose_ki_kernel<<<(S * ID) / 256, 256, 0, stream>>>(ki, kiT);

    // --- indexer scores + exact top-k + bitmap
    iscore_kernel<<<dim3(S, S / 256), 256, 0, stream>>>(qi, kiT, iw, iscore);
    topk_kernel<<<S, 256, 0, stream>>>(iscore, selidx, selcnt);
    mask_build<<<S, 256, 0, stream>>>(selidx, selcnt, msk);

    // --- dense-causal masked flash attention
    fattn<<<dim3(S / 64, NH), 256, 0, stream>>>(qb, kb, vT, msk, attn_b);

    // --- out = attn @ Wo
    wtrans<<<dim3(CDIV(NH * DV, 64), CDIV(HID, 64)), 256, 0, stream>>>(Wo, poolw, NH * DV, HID);
    gemm_bt<<<dim3(HID / 128, S / 128), 256, 0, stream>>>(attn_b, poolw, out, S, HID, NH * DV);

    (void)in_sizes; (void)n_in; (void)out_size; (void)ws_size; (void)o;
}

// Round 3
// 712.042 us; speedup vs baseline: 8.9303x; 1.3023x over previous
//
#include <hip/hip_runtime.h>
#include <math.h>
#include <stdint.h>

#define S 2048
#define HID 2048
#define NH 16
#define QL 1536
#define KVL 512
#define DN 128
#define DR 64
#define DV 128
#define DQ 192
#define IH 4
#define ID 128
#define TOPK 1024

#define CDIV(a,b) (((a)+(b)-1)/(b))

typedef float f32x4 __attribute__((ext_vector_type(4)));
typedef short bf16x8 __attribute__((ext_vector_type(8)));

__device__ __forceinline__ ushort f2b(float f) {
    uint32_t u = __float_as_uint(f);
    u += 0x7fffu + ((u >> 16) & 1u);
    return (ushort)(u >> 16);
}

#define GLL16(g, l)                                                            \
    __builtin_amdgcn_global_load_lds(                                          \
        (const __attribute__((address_space(1))) void*)(g),                    \
        (__attribute__((address_space(3))) void*)(l), 16, 0, 0)

// ============ bf16 MFMA GEMM (m97-style): C[M,N]f32 = A[M,K] @ BT[N,K] ======
// M mult of 128; K mult of 32. Tiles 128x128, BK=32, global_load_lds staging.
__global__ __launch_bounds__(256) void gemm_bt(const ushort* __restrict__ A,
                                               const ushort* __restrict__ BT,
                                               float* __restrict__ C,
                                               int M, int N, int K) {
    __shared__ ushort As[128 * 32];   // unpadded: lane-ordered DMA layout
    __shared__ ushort Bs[128 * 32];
    const int tid = threadIdx.x;
    const int w = tid >> 6, l = tid & 63;
    const int quad = l >> 4, lane = l & 15;
    const int row0 = blockIdx.y * 128, col0 = blockIdx.x * 128;
    const int wr = (w >> 1) * 64, wc = (w & 1) * 64;
    f32x4 acc[4][4];
#pragma unroll
    for (int i = 0; i < 4; i++)
#pragma unroll
        for (int j = 0; j < 4; j++) acc[i][j] = (f32x4)0.f;

    // staging: wave w covers tile rows [w*32, w*32+32); lane l -> row w*32+l/4,
    // col (l&3)*8; second issue +16 rows. LDS dest = natural row-major address
    // == wave-uniform base + lane*16B (required by global_load_lds).
    const int srow = w * 32 + (l >> 2);
    const int c8 = (l & 3) * 8;
    const ushort* pa0 = A + (size_t)(row0 + srow) * K + c8;
    const ushort* pa1 = A + (size_t)(row0 + srow + 16) * K + c8;
    int bn0 = col0 + srow;      if (bn0 > N - 1) bn0 = N - 1;
    int bn1 = col0 + srow + 16; if (bn1 > N - 1) bn1 = N - 1;
    const ushort* pb0 = BT + (size_t)bn0 * K + c8;
    const ushort* pb1 = BT + (size_t)bn1 * K + c8;
    ushort* sa0 = As + srow * 32 + c8;
    ushort* sa1 = sa0 + 16 * 32;
    ushort* sb0 = Bs + srow * 32 + c8;
    ushort* sb1 = sb0 + 16 * 32;

    for (int k0 = 0; k0 < K; k0 += 32) {
        __syncthreads();   // prev-iter frag reads done before overwrite
        GLL16(pa0 + k0, sa0);
        GLL16(pa1 + k0, sa1);
        GLL16(pb0 + k0, sb0);
        GLL16(pb1 + k0, sb1);
        __syncthreads();   // drain DMA (compiler emits vmcnt(0) before barrier)
        bf16x8 af[4], bf[4];
#pragma unroll
        for (int mi = 0; mi < 4; mi++)
            af[mi] = *(const bf16x8*)(As + (wr + mi * 16 + lane) * 32 + quad * 8);
#pragma unroll
        for (int ni = 0; ni < 4; ni++)
            bf[ni] = *(const bf16x8*)(Bs + (wc + ni * 16 + lane) * 32 + quad * 8);
#pragma unroll
        for (int mi = 0; mi < 4; mi++)
#pragma unroll
            for (int ni = 0; ni < 4; ni++)
                acc[mi][ni] = __builtin_amdgcn_mfma_f32_16x16x32_bf16(af[mi], bf[ni], acc[mi][ni], 0, 0, 0);
    }
#pragma unroll
    for (int mi = 0; mi < 4; mi++)
#pragma unroll
        for (int ni = 0; ni < 4; ni++)
#pragma unroll
            for (int r = 0; r < 4; r++) {
                int row = row0 + wr + mi * 16 + quad * 4 + r;
                int col = col0 + wc + ni * 16 + lane;
                if (col < N) C[(size_t)row * N + col] = acc[mi][ni][r];
            }
}

// ============ weight transpose+convert: W[K,N]f32 -> WT[N,K]bf16 =============
__global__ __launch_bounds__(256) void wtrans(const float* __restrict__ W, ushort* __restrict__ WT,
                                              int K, int N) {
    __shared__ float t[64][65];
    int k0 = blockIdx.x * 64, n0 = blockIdx.y * 64;
    int rr = threadIdx.x >> 6, cc = threadIdx.x & 63;
#pragma unroll
    for (int p = 0; p < 16; p++) {
        int k = k0 + p * 4 + rr, n = n0 + cc;
        t[p * 4 + rr][cc] = (k < K && n < N) ? W[(size_t)k * N + n] : 0.f;
    }
    __syncthreads();
#pragma unroll
    for (int p = 0; p < 16; p++) {
        int n = n0 + p * 4 + rr, k = k0 + cc;
        if (n < N && k < K) WT[(size_t)n * K + k] = f2b(t[cc][p * 4 + rr]);
    }
}

// ============ elementwise f32 -> bf16 (n mult of 1024) =======================
__global__ void cvt_bf16(const float* __restrict__ in, ushort* __restrict__ out) {
    int i = blockIdx.x * 256 + threadIdx.x;
    float4 v = *(const float4*)(in + (size_t)i * 4);
    uint32_t lo = (uint32_t)f2b(v.x) | ((uint32_t)f2b(v.y) << 16);
    uint32_t hi = (uint32_t)f2b(v.z) | ((uint32_t)f2b(v.w) << 16);
    *(uint2*)(out + (size_t)i * 4) = make_uint2(lo, hi);
}

// ============ rmsnorm f32 in -> bf16 out =====================================
__global__ __launch_bounds__(256) void rmsnorm_b(const float* __restrict__ in, int istride,
                                                 ushort* __restrict__ out, int ostride,
                                                 const float* __restrict__ w, int L) {
    int row = blockIdx.x, tid = threadIdx.x;
    const float* xr = in + (size_t)row * istride;
    ushort* yr = out + (size_t)row * ostride;
    __shared__ float red[256];
    float ss = 0.f;
    for (int i = tid; i < L; i += 256) { float v = xr[i]; ss += v * v; }
    red[tid] = ss; __syncthreads();
    for (int st = 128; st > 0; st >>= 1) {
        if (tid < st) red[tid] += red[tid + st];
        __syncthreads();
    }
    float scale = rsqrtf(red[0] / (float)L + 1e-6f);
    for (int i = tid; i < L; i += 256) yr[i] = f2b(xr[i] * scale * w[i]);
}

// ============ rope q (interleaved, dims 128..191) + scale -> qb[NH][S][192] ==
__global__ void rope_q_b(const float* __restrict__ qf, ushort* __restrict__ qb,
                         const float* __restrict__ cosb, const float* __restrict__ sinb) {
    int idx = blockIdx.x * 256 + threadIdx.x;  // S*NH*96
    int p = idx % 96, h = (idx / 96) & 15, t = idx / (96 * 16);
    const float sc = 0.07216878364870322f;  // 192^-0.5 folded into Q
    const float* src = qf + (size_t)t * 3072 + h * 192;
    ushort* dst = qb + ((size_t)h * S + t) * 192;
    if (p < 64) {
        dst[2 * p]     = f2b(src[2 * p] * sc);
        dst[2 * p + 1] = f2b(src[2 * p + 1] * sc);
    } else {
        int j = p - 64;
        float c = cosb[t * 32 + j], s = sinb[t * 32 + j];
        float xr = src[128 + 2 * j], xi = src[128 + 2 * j + 1];
        dst[128 + 2 * j]     = f2b((xr * c - xi * s) * sc);
        dst[128 + 2 * j + 1] = f2b((xr * s + xi * c) * sc);
    }
}

// ============ rope k_pe: kvf[:,512:576] -> kpe[S,64] f32 =====================
__global__ void rope_kpe_kernel(const float* __restrict__ kvf, float* __restrict__ kpe,
                                const float* __restrict__ cosb, const float* __restrict__ sinb) {
    int idx = blockIdx.x * 256 + threadIdx.x;  // S*32
    int j = idx & 31, t = idx >> 5;
    float c = cosb[t * 32 + j], s = sinb[t * 32 + j];
    const float* p = kvf + (size_t)t * (KVL + DR) + KVL + 2 * j;
    float xr = p[0], xi = p[1];
    kpe[t * 64 + 2 * j] = xr * c - xi * s;
    kpe[t * 64 + 2 * j + 1] = xr * s + xi * c;
}

// ============ build kb[NH][S][192] bf16 from kvexp + kpe =====================
__global__ void build_kb(const float* __restrict__ kvexp, const float* __restrict__ kpe,
                         ushort* __restrict__ kb) {
    int idx = blockIdx.x * 256 + threadIdx.x;  // NH*S*192
    int d = idx % 192, s = (idx / 192) & 2047, h = idx / (192 * 2048);
    float v = (d < 128) ? kvexp[(size_t)s * 4096 + h * 256 + d] : kpe[s * 64 + (d - 128)];
    kb[idx] = f2b(v);
}

// ============ vT[NH][128][S] bf16 = transpose of kvexp V part ================
__global__ __launch_bounds__(256) void vtrans(const float* __restrict__ kvexp, ushort* __restrict__ vT) {
    __shared__ float t[64][65];
    int s0 = blockIdx.x * 64, d0 = blockIdx.y * 64, h = blockIdx.z;
    int rr = threadIdx.x >> 6, cc = threadIdx.x & 63;
#pragma unroll
    for (int p = 0; p < 16; p++)
        t[p * 4 + rr][cc] = kvexp[(size_t)(s0 + p * 4 + rr) * 4096 + h * 256 + 128 + d0 + cc];
    __syncthreads();
#pragma unroll
    for (int p = 0; p < 16; p++)
        vT[((size_t)h * 128 + d0 + p * 4 + rr) * S + s0 + cc] = f2b(t[cc][p * 4 + rr]);
}

// ============ rope non-interleaved on qi first 64 dims (qi: [S,4,128] f32) ===
__global__ void rope_qi_kernel(float* __restrict__ qi, const float* __restrict__ cosb,
                               const float* __restrict__ sinb) {
    int idx = blockIdx.x * 256 + threadIdx.x;  // S*4*32
    int j = idx & 31, h = (idx >> 5) & 3, t = idx >> 7;
    float c = cosb[t * 32 + j], s = sinb[t * 32 + j];
    float* p = qi + ((size_t)t * IH + h) * ID;
    float x1 = p[j], x2 = p[j + 32];
    p[j] = x1 * c - x2 * s;
    p[j + 32] = x1 * s + x2 * c;
}

// ============ layernorm + rope (non-interleaved, first 64) on ki rows ========
__global__ __launch_bounds__(128) void ki_ln_rope_kernel(float* __restrict__ ki,
                                                         const float* __restrict__ g,
                                                         const float* __restrict__ bb,
                                                         const float* __restrict__ cosb,
                                                         const float* __restrict__ sinb) {
    int t = blockIdx.x, tid = threadIdx.x;
    float* p = ki + (size_t)t * ID;
    __shared__ float s1[128], s2m[128];
    float v = p[tid];
    s1[tid] = v; s2m[tid] = v * v; __syncthreads();
    for (int st = 64; st > 0; st >>= 1) {
        if (tid < st) { s1[tid] += s1[tid + st]; s2m[tid] += s2m[tid + st]; }
        __syncthreads();
    }
    float mu = s1[0] / 128.f;
    float var = s2m[0] / 128.f - mu * mu;
    float y = (v - mu) * rsqrtf(var + 1e-6f) * g[tid] + bb[tid];
    __syncthreads();
    s1[tid] = y; __syncthreads();
    if (tid >= 64) {
        p[tid] = y;
    } else if (tid < 32) {
        float c = cosb[t * 32 + tid], s = sinb[t * 32 + tid];
        float x1 = s1[tid], x2 = s1[tid + 32];
        p[tid] = x1 * c - x2 * s;
        p[tid + 32] = x1 * s + x2 * c;
    }
}

// ============ transpose ki [S,128] -> kiT [128,S] ============================
__global__ void transpose_ki_kernel(const float* __restrict__ ki, float* __restrict__ kiT) {
    int idx = blockIdx.x * 256 + threadIdx.x;  // S*128
    int t = idx >> 7, d = idx & 127;
    kiT[(size_t)d * S + t] = ki[idx];
}

// ============ iw[t][j] = x[t] . IWproj[:,j] ==================================
__global__ __launch_bounds__(256) void iw_kernel(const float* __restrict__ x,
                                                 const float* __restrict__ IWproj,
                                                 float* __restrict__ iw) {
    int t = blockIdx.x, tid = threadIdx.x;
    __shared__ float red[256];
    float p0 = 0.f, p1 = 0.f, p2 = 0.f, p3 = 0.f;
    for (int k = tid; k < HID; k += 256) {
        float a = x[(size_t)t * HID + k];
        const float* wr = IWproj + k * 4;
        p0 += a * wr[0]; p1 += a * wr[1]; p2 += a * wr[2]; p3 += a * wr[3];
    }
#pragma unroll
    for (int j = 0; j < 4; j++) {
        float v = (j == 0) ? p0 : (j == 1) ? p1 : (j == 2) ? p2 : p3;
        red[tid] = v; __syncthreads();
        for (int st = 128; st > 0; st >>= 1) {
            if (tid < st) red[tid] += red[tid + st];
            __syncthreads();
        }
        if (tid == 0) iw[t * 4 + j] = red[0];
        __syncthreads();
    }
}

// ============ indexer score (fp32, 4 cols/thread, causal region only) ========
__global__ __launch_bounds__(256) void iscore4(const float* __restrict__ qi,
                                               const float* __restrict__ kiT,
                                               const float* __restrict__ iw,
                                               float* __restrict__ iscore) {
    int t = blockIdx.x;
    int s0 = blockIdx.y * 1024;
    if (s0 > t) return;               // uniform early-out
    int s = s0 + threadIdx.x * 4;
    __shared__ float qs[4 * ID];
    __shared__ float ws4[4];
    for (int i = threadIdx.x; i < 4 * ID; i += 256) qs[i] = qi[(size_t)t * (4 * ID) + i];
    if (threadIdx.x < 4) ws4[threadIdx.x] = iw[t * 4 + threadIdx.x] * 0.04419417382415922f;
    __syncthreads();
    if (s > t) return;
    float a[4][4];
#pragma unroll
    for (int h = 0; h < 4; h++)
#pragma unroll
        for (int c = 0; c < 4; c++) a[h][c] = 0.f;
    for (int d = 0; d < ID; d++) {
        float4 kv = *(const float4*)(kiT + (size_t)d * S + s);
#pragma unroll
        for (int h = 0; h < 4; h++) {
            float qv = qs[h * ID + d];
            a[h][0] += qv * kv.x; a[h][1] += qv * kv.y;
            a[h][2] += qv * kv.z; a[h][3] += qv * kv.w;
        }
    }
#pragma unroll
    for (int c = 0; c < 4; c++) {
        if (s + c > t) break;
        float sc = fmaxf(a[0][c], 0.f) * ws4[0] + fmaxf(a[1][c], 0.f) * ws4[1] +
                   fmaxf(a[2][c], 0.f) * ws4[2] + fmaxf(a[3][c], 0.f) * ws4[3];
        iscore[(size_t)t * S + s + c] = sc;
    }
}

// ============ exact top-k -> bitmask (registers-resident radix select) =======
__device__ inline unsigned sortable_u32(float f) {
    unsigned u = __float_as_uint(f);
    return (u & 0x80000000u) ? ~u : (u | 0x80000000u);
}

__global__ __launch_bounds__(256) void topk_mask(const float* __restrict__ iscore,
                                                 uint32_t* __restrict__ msk) {
    int t = blockIdx.x, tid = threadIdx.x;
    uint32_t* mrow = msk + (size_t)t * 64;
    if (t < TOPK) {                        // all causal keys kept
        if (tid < 64) {
            int full = (t + 1) >> 5;
            uint32_t wv = (tid < full) ? 0xFFFFFFFFu : 0u;
            if (tid == full) { int rem = (t + 1) & 31; wv = rem ? ((1u << rem) - 1u) : 0u; }
            mrow[tid] = wv;
        }
        return;
    }
    const float* row = iscore + (size_t)t * S;
    const int n = t + 1;
    const int wv = tid >> 6;
    __shared__ int hist[4][256];
    __shared__ int scan[256];
    __shared__ int bsel, ksel;
    __shared__ uint32_t bytes[256];

    // 8 contiguous elements per thread, kept in registers for all passes
    int jb = tid * 8;
    float4 v0 = *(const float4*)(row + jb);
    float4 v1 = *(const float4*)(row + jb + 4);
    uint32_t lsu[8];
    {
        float vv[8] = {v0.x, v0.y, v0.z, v0.w, v1.x, v1.y, v1.z, v1.w};
#pragma unroll
        for (int i = 0; i < 8; i++)
            lsu[i] = (jb + i < n) ? sortable_u32(vv[i]) : 0u;   // pad < any real
    }
    unsigned prefix = 0, prefmask = 0;
    int k = TOPK;
    for (int pass = 0; pass < 4; pass++) {
        int shift = 24 - pass * 8;
#pragma unroll
        for (int r = 0; r < 4; r++) hist[r][tid] = 0;
        __syncthreads();
#pragma unroll
        for (int i = 0; i < 8; i++) {
            uint32_t u = lsu[i];
            if ((u & prefmask) == prefix) atomicAdd(&hist[wv][(u >> shift) & 255], 1);
        }
        __syncthreads();
        int h = hist[0][tid] + hist[1][tid] + hist[2][tid] + hist[3][tid];
        scan[tid] = h; __syncthreads();
        for (int st = 1; st < 256; st <<= 1) {      // inclusive suffix sum
            int a = scan[tid];
            int b = (tid + st < 256) ? scan[tid + st] : 0;
            __syncthreads();
            scan[tid] = a + b;
            __syncthreads();
        }
        int snext = (tid < 255) ? scan[tid + 1] : 0;
        if (scan[tid] >= k && snext < k) { bsel = tid; ksel = k - snext; }
        __syncthreads();
        prefix |= ((unsigned)bsel) << shift;
        prefmask |= 0xFFu << shift;
        k = ksel;
        __syncthreads();
    }
    const unsigned u_thr = prefix;
    const int need = k;                    // equals to keep, lowest index first
    uint32_t gtbits = 0, eqbits = 0;
    int eqcnt = 0;
#pragma unroll
    for (int i = 0; i < 8; i++) {
        uint32_t u = lsu[i];
        if (u > u_thr) gtbits |= 1u << i;
        else if (u == u_thr) { eqbits |= 1u << i; eqcnt++; }
    }
    scan[tid] = eqcnt; __syncthreads();
    for (int st = 1; st < 256; st <<= 1) {          // inclusive prefix sum
        int a = scan[tid];
        int b = (tid >= st) ? scan[tid - st] : 0;
        __syncthreads();
        scan[tid] = a + b;
        __syncthreads();
    }
    int room = need - (scan[tid] - eqcnt);          // exclusive rank
    uint32_t keep = 0;
#pragma unroll
    for (int i = 0; i < 8; i++)
        if ((eqbits >> i) & 1u) { if (room > 0) { keep |= 1u << i; room--; } }
    bytes[tid] = gtbits | keep;
    __syncthreads();
    if (tid < 64)
        mrow[tid] = bytes[tid * 4] | (bytes[tid * 4 + 1] << 8) |
                    (bytes[tid * 4 + 2] << 16) | (bytes[tid * 4 + 3] << 24);
}

// ============ dense-causal masked flash attention (bf16 MFMA) ================
__global__ __launch_bounds__(256) void fattn(const ushort* __restrict__ qb,
                                             const ushort* __restrict__ kb,
                                             const ushort* __restrict__ vT,
                                             const uint32_t* __restrict__ msk,
                                             ushort* __restrict__ attn_b) {
    __shared__ ushort Ks[64 * 200];
    __shared__ ushort Vs[128 * 72];
    __shared__ float Sc[64 * 66];
    __shared__ ushort Pm[64 * 72];
    __shared__ float mrow[64], lrow[64], arow[64];
    __shared__ float red[256];
    const int tid = threadIdx.x;
    const int w = tid >> 6, l = tid & 63, quad = l >> 4, lane = l & 15;
    const int h = blockIdx.y, q0 = blockIdx.x * 64;

    bf16x8 qf[6];
    {
        const ushort* qp = qb + ((size_t)h * S + q0 + w * 16 + lane) * 192;
#pragma unroll
        for (int ks = 0; ks < 6; ks++) qf[ks] = *(const bf16x8*)(qp + ks * 32 + quad * 8);
    }
    f32x4 oacc[8];
#pragma unroll
    for (int i = 0; i < 8; i++) oacc[i] = (f32x4)0.f;
    if (tid < 64) { mrow[tid] = -1e30f; lrow[tid] = 0.f; }

    const int ktiles = blockIdx.x + 1;
    for (int kt = 0; kt < ktiles; kt++) {
        const int s0 = kt * 64;
        __syncthreads();
        {
            const ushort* src = kb + ((size_t)h * S + s0 + (tid >> 2)) * 192;
            ushort* dst = Ks + (tid >> 2) * 200;
#pragma unroll
            for (int i = 0; i < 6; i++) {
                int c = (tid & 3) + 4 * i;
                *(uint4*)(dst + c * 8) = *(const uint4*)(src + c * 8);
            }
        }
        {
            const ushort* src = vT + ((size_t)h * 128 + (tid >> 1)) * S + s0;
            ushort* dst = Vs + (tid >> 1) * 72;
#pragma unroll
            for (int i = 0; i < 4; i++) {
                int c = (tid & 1) + 2 * i;
                *(uint4*)(dst + c * 8) = *(const uint4*)(src + c * 8);
            }
        }
        __syncthreads();
#pragma unroll
        for (int kq = 0; kq < 4; kq++) {
            f32x4 sacc = (f32x4)0.f;
#pragma unroll
            for (int ks = 0; ks < 6; ks++) {
                bf16x8 bfr = *(const bf16x8*)(Ks + (kq * 16 + lane) * 200 + ks * 32 + quad * 8);
                sacc = __builtin_amdgcn_mfma_f32_16x16x32_bf16(qf[ks], bfr, sacc, 0, 0, 0);
            }
#pragma unroll
            for (int r = 0; r < 4; r++)
                Sc[(w * 16 + quad * 4 + r) * 66 + kq * 16 + lane] = sacc[r];
        }
        __syncthreads();
        {
            const int r = tid >> 2, g = tid & 3;
            const uint32_t mword = msk[(q0 + r) * 64 + ((s0 + g * 16) >> 5)];
            const int sh = (g & 1) * 16;
            float vals[16];
            float vmax = -1e30f;
#pragma unroll
            for (int i = 0; i < 16; i++) {
                float v = Sc[r * 66 + g * 16 + i];
                if (!((mword >> (sh + i)) & 1u)) v = -1e30f;
                vals[i] = v;
                vmax = fmaxf(vmax, v);
            }
            red[tid] = vmax;
            __syncthreads();
            float m_tile = fmaxf(fmaxf(red[r * 4 + 0], red[r * 4 + 1]),
                                 fmaxf(red[r * 4 + 2], red[r * 4 + 3]));
            float m_old = mrow[r];
            float m_new = fmaxf(m_old, m_tile);
            float psum = 0.f;
#pragma unroll
            for (int i = 0; i < 16; i++) {
                float e = (vals[i] < -1e29f) ? 0.f : __expf(vals[i] - m_new);
                psum += e;
                Pm[r * 72 + g * 16 + i] = f2b(e);
            }
            __syncthreads();
            red[tid] = psum;
            __syncthreads();
            if (g == 0) {
                float a = __expf(m_old - m_new);
                lrow[r] = lrow[r] * a + (red[r * 4] + red[r * 4 + 1] + red[r * 4 + 2] + red[r * 4 + 3]);
                mrow[r] = m_new;
                arow[r] = a;
            }
            __syncthreads();
        }
        {
            float al[4];
#pragma unroll
            for (int r = 0; r < 4; r++) al[r] = arow[w * 16 + quad * 4 + r];
            bf16x8 pfr[2];
#pragma unroll
            for (int k2 = 0; k2 < 2; k2++)
                pfr[k2] = *(const bf16x8*)(Pm + (w * 16 + lane) * 72 + k2 * 32 + quad * 8);
#pragma unroll
            for (int nt = 0; nt < 8; nt++) {
#pragma unroll
                for (int r = 0; r < 4; r++) oacc[nt][r] *= al[r];
#pragma unroll
                for (int k2 = 0; k2 < 2; k2++) {
                    bf16x8 vfr = *(const bf16x8*)(Vs + (nt * 16 + lane) * 72 + k2 * 32 + quad * 8);
                    oacc[nt] = __builtin_amdgcn_mfma_f32_16x16x32_bf16(pfr[k2], vfr, oacc[nt], 0, 0, 0);
                }
            }
        }
    }
    {
        float inv[4];
#pragma unroll
        for (int r = 0; r < 4; r++) inv[r] = 1.f / lrow[w * 16 + quad * 4 + r];
#pragma unroll
        for (int nt = 0; nt < 8; nt++)
#pragma unroll
            for (int r = 0; r < 4; r++) {
                int row = q0 + w * 16 + quad * 4 + r;
                attn_b[(size_t)row * 2048 + h * 128 + nt * 16 + lane] = f2b(oacc[nt][r] * inv[r]);
            }
    }
}

// ============ host ===========================================================
extern "C" void kernel_launch(void* const* d_in, const int* in_sizes, int n_in,
                              void* d_out, int out_size, void* d_ws, size_t ws_size,
                              hipStream_t stream) {
    const float* x        = (const float*)d_in[0];
    const float* cosb     = (const float*)d_in[1];
    const float* sinb     = (const float*)d_in[2];
    const float* Wq_a     = (const float*)d_in[4];
    const float* q_norm_w = (const float*)d_in[5];
    const float* Wq_b     = (const float*)d_in[6];
    const float* Wkv_a    = (const float*)d_in[7];
    const float* kv_norm_w= (const float*)d_in[8];
    const float* Wkv_b    = (const float*)d_in[9];
    const float* Wo       = (const float*)d_in[10];
    const float* IWq_b    = (const float*)d_in[11];
    const float* IWk      = (const float*)d_in[12];
    const float* Ik_norm_w= (const float*)d_in[13];
    const float* Ik_norm_b= (const float*)d_in[14];
    const float* IWproj   = (const float*)d_in[15];
    float* out = (float*)d_out;

    char* ws = (char*)d_ws;
    size_t o = 0;
    auto take = [&](size_t b) { char* p = ws + o; o += (b + 255) & ~(size_t)255; return p; };
    ushort* xb     = (ushort*)take((size_t)S * HID * 2);
    ushort* qrb    = (ushort*)take((size_t)S * QL * 2);
    ushort* qb     = (ushort*)take((size_t)NH * S * DQ * 2);
    ushort* kvnb   = (ushort*)take((size_t)S * KVL * 2);
    float*  kpe    = (float*)take((size_t)S * DR * 4);
    ushort* kb     = (ushort*)take((size_t)NH * S * DQ * 2);
    ushort* vT     = (ushort*)take((size_t)NH * DV * S * 2);
    float*  iw     = (float*)take((size_t)S * IH * 4);
    uint32_t* msk  = (uint32_t*)take((size_t)S * 64 * 4);
    ushort* poolw  = (ushort*)take((size_t)3072 * 1536 * 2);       // largest WT
    char*   poola  = take((size_t)33554432);                       // f32 activation pool
    char*   poolb  = take((size_t)16777216);                       // iscore / attn_b

    float* qr_f   = (float*)poola;             // [S][QL]
    float* qf_f   = (float*)poola;             // [S][3072]
    float* kvf_f  = (float*)poola;             // [S][576]
    float* kvexp  = (float*)poola;             // [S][4096]
    float* qi     = (float*)poola;             // [S][512]   (after kvexp dead)
    float* ki     = (float*)(poola + 4194304); // [S][128]
    float* kiT    = (float*)(poola + 5242880); // [128][S]
    float* iscore = (float*)poolb;             // [S][S]
    ushort* attn_b = (ushort*)poolb;           // [S][2048] (after topk consumed iscore)

    // --- x -> bf16
    cvt_bf16<<<(S * HID) / 1024, 256, 0, stream>>>(x, xb);

    // --- qr = rmsnorm(x @ Wq_a)
    wtrans<<<dim3(CDIV(HID, 64), CDIV(QL, 64)), 256, 0, stream>>>(Wq_a, poolw, HID, QL);
    gemm_bt<<<dim3(QL / 128, S / 128), 256, 0, stream>>>(xb, poolw, qr_f, S, QL, HID);
    rmsnorm_b<<<S, 256, 0, stream>>>(qr_f, QL, qrb, QL, q_norm_w, QL);

    // --- q = qr @ Wq_b ; rope+scale -> qb bf16 [NH][S][192]
    wtrans<<<dim3(CDIV(QL, 64), CDIV(NH * DQ, 64)), 256, 0, stream>>>(Wq_b, poolw, QL, NH * DQ);
    gemm_bt<<<dim3((NH * DQ) / 128, S / 128), 256, 0, stream>>>(qrb, poolw, qf_f, S, NH * DQ, QL);
    rope_q_b<<<(S * NH * 96) / 256, 256, 0, stream>>>(qf_f, qb, cosb, sinb);

    // --- kv_full = x @ Wkv_a ; norm + rope
    wtrans<<<dim3(CDIV(HID, 64), CDIV(KVL + DR, 64)), 256, 0, stream>>>(Wkv_a, poolw, HID, KVL + DR);
    gemm_bt<<<dim3(CDIV(KVL + DR, 128), S / 128), 256, 0, stream>>>(xb, poolw, kvf_f, S, KVL + DR, HID);
    rmsnorm_b<<<S, 256, 0, stream>>>(kvf_f, KVL + DR, kvnb, KVL, kv_norm_w, KVL);
    rope_kpe_kernel<<<(S * 32) / 256, 256, 0, stream>>>(kvf_f, kpe, cosb, sinb);

    // --- kv_exp = kvn @ Wkv_b ; build kb / vT
    wtrans<<<dim3(CDIV(KVL, 64), CDIV(NH * (DN + DV), 64)), 256, 0, stream>>>(Wkv_b, poolw, KVL, NH * (DN + DV));
    gemm_bt<<<dim3((NH * (DN + DV)) / 128, S / 128), 256, 0, stream>>>(kvnb, poolw, kvexp, S, NH * (DN + DV), KVL);
    build_kb<<<(NH * S * DQ) / 256, 256, 0, stream>>>(kvexp, kpe, kb);
    vtrans<<<dim3(S / 64, DV / 64, NH), 256, 0, stream>>>(kvexp, vT);

    // --- indexer inputs (fp32 precision-sensitive path)
    wtrans<<<dim3(CDIV(QL, 64), CDIV(IH * ID, 64)), 256, 0, stream>>>(IWq_b, poolw, QL, IH * ID);
    gemm_bt<<<dim3((IH * ID) / 128, S / 128), 256, 0, stream>>>(qrb, poolw, qi, S, IH * ID, QL);
    rope_qi_kernel<<<(S * IH * 32) / 256, 256, 0, stream>>>(qi, cosb, sinb);
    wtrans<<<dim3(CDIV(HID, 64), CDIV(ID, 64)), 256, 0, stream>>>(IWk, poolw, HID, ID);
    gemm_bt<<<dim3(ID / 128, S / 128), 256, 0, stream>>>(xb, poolw, ki, S, ID, HID);
    ki_ln_rope_kernel<<<S, 128, 0, stream>>>(ki, Ik_norm_w, Ik_norm_b, cosb, sinb);
    iw_kernel<<<S, 256, 0, stream>>>(x, IWproj, iw);
    transpose_ki_kernel<<<(S * ID) / 256, 256, 0, stream>>>(ki, kiT);

    // --- indexer scores + exact top-k -> bitmap
    iscore4<<<dim3(S, S / 1024), 256, 0, stream>>>(qi, kiT, iw, iscore);
    topk_mask<<<S, 256, 0, stream>>>(iscore, msk);

    // --- dense-causal masked flash attention
    fattn<<<dim3(S / 64, NH), 256, 0, stream>>>(qb, kb, vT, msk, attn_b);

    // --- out = attn @ Wo
    wtrans<<<dim3(CDIV(NH * DV, 64), CDIV(HID, 64)), 256, 0, stream>>>(Wo, poolw, NH * DV, HID);
    gemm_bt<<<dim3(HID / 128, S / 128), 256, 0, stream>>>(attn_b, poolw, out, S, HID, NH * DV);

    (void)in_sizes; (void)n_in; (void)out_size; (void)ws_size; (void)o;
}

// Round 4
// 700.334 us; speedup vs baseline: 9.0796x; 1.0167x over previous
//
#include <hip/hip_runtime.h>
#include <math.h>
#include <stdint.h>

#define S 2048
#define HID 2048
#define NH 16
#define QL 1536
#define KVL 512
#define DN 128
#define DR 64
#define DV 128
#define DQ 192
#define IH 4
#define ID 128
#define TOPK 1024

#define CDIV(a,b) (((a)+(b)-1)/(b))

typedef float f32x4 __attribute__((ext_vector_type(4)));
typedef short bf16x8 __attribute__((ext_vector_type(8)));

__device__ __forceinline__ ushort f2b(float f) {
    uint32_t u = __float_as_uint(f);
    u += 0x7fffu + ((u >> 16) & 1u);
    return (ushort)(u >> 16);
}

#define GLL16(g, l)                                                            \
    __builtin_amdgcn_global_load_lds(                                          \
        (const __attribute__((address_space(1))) void*)(g),                    \
        (__attribute__((address_space(3))) void*)(l), 16, 0, 0)

// ============ bf16 MFMA GEMM (m97-style): C[M,N]f32 = A[M,K] @ BT[N,K] ======
__global__ __launch_bounds__(256) void gemm_bt(const ushort* __restrict__ A,
                                               const ushort* __restrict__ BT,
                                               float* __restrict__ C,
                                               int M, int N, int K) {
    __shared__ ushort As[128 * 32];   // unpadded: lane-ordered DMA layout
    __shared__ ushort Bs[128 * 32];
    const int tid = threadIdx.x;
    const int w = tid >> 6, l = tid & 63;
    const int quad = l >> 4, lane = l & 15;
    const int row0 = blockIdx.y * 128, col0 = blockIdx.x * 128;
    const int wr = (w >> 1) * 64, wc = (w & 1) * 64;
    f32x4 acc[4][4];
#pragma unroll
    for (int i = 0; i < 4; i++)
#pragma unroll
        for (int j = 0; j < 4; j++) acc[i][j] = (f32x4)0.f;

    const int srow = w * 32 + (l >> 2);
    const int c8 = (l & 3) * 8;
    const ushort* pa0 = A + (size_t)(row0 + srow) * K + c8;
    const ushort* pa1 = A + (size_t)(row0 + srow + 16) * K + c8;
    int bn0 = col0 + srow;      if (bn0 > N - 1) bn0 = N - 1;
    int bn1 = col0 + srow + 16; if (bn1 > N - 1) bn1 = N - 1;
    const ushort* pb0 = BT + (size_t)bn0 * K + c8;
    const ushort* pb1 = BT + (size_t)bn1 * K + c8;
    ushort* sa0 = As + srow * 32 + c8;
    ushort* sa1 = sa0 + 16 * 32;
    ushort* sb0 = Bs + srow * 32 + c8;
    ushort* sb1 = sb0 + 16 * 32;

    for (int k0 = 0; k0 < K; k0 += 32) {
        __syncthreads();
        GLL16(pa0 + k0, sa0);
        GLL16(pa1 + k0, sa1);
        GLL16(pb0 + k0, sb0);
        GLL16(pb1 + k0, sb1);
        __syncthreads();
        bf16x8 af[4], bf[4];
#pragma unroll
        for (int mi = 0; mi < 4; mi++)
            af[mi] = *(const bf16x8*)(As + (wr + mi * 16 + lane) * 32 + quad * 8);
#pragma unroll
        for (int ni = 0; ni < 4; ni++)
            bf[ni] = *(const bf16x8*)(Bs + (wc + ni * 16 + lane) * 32 + quad * 8);
#pragma unroll
        for (int mi = 0; mi < 4; mi++)
#pragma unroll
            for (int ni = 0; ni < 4; ni++)
                acc[mi][ni] = __builtin_amdgcn_mfma_f32_16x16x32_bf16(af[mi], bf[ni], acc[mi][ni], 0, 0, 0);
    }
#pragma unroll
    for (int mi = 0; mi < 4; mi++)
#pragma unroll
        for (int ni = 0; ni < 4; ni++)
#pragma unroll
            for (int r = 0; r < 4; r++) {
                int row = row0 + wr + mi * 16 + quad * 4 + r;
                int col = col0 + wc + ni * 16 + lane;
                if (col < N) C[(size_t)row * N + col] = acc[mi][ni][r];
            }
}

// ============ weight transpose+convert: W[K,N]f32 -> WT[N,K]bf16 =============
__global__ __launch_bounds__(256) void wtrans(const float* __restrict__ W, ushort* __restrict__ WT,
                                              int K, int N) {
    __shared__ float t[64][65];
    int k0 = blockIdx.x * 64, n0 = blockIdx.y * 64;
    int rr = threadIdx.x >> 6, cc = threadIdx.x & 63;
#pragma unroll
    for (int p = 0; p < 16; p++) {
        int k = k0 + p * 4 + rr, n = n0 + cc;
        t[p * 4 + rr][cc] = (k < K && n < N) ? W[(size_t)k * N + n] : 0.f;
    }
    __syncthreads();
#pragma unroll
    for (int p = 0; p < 16; p++) {
        int n = n0 + p * 4 + rr, k = k0 + cc;
        if (n < N && k < K) WT[(size_t)n * K + k] = f2b(t[cc][p * 4 + rr]);
    }
}

// ============ elementwise f32 -> bf16 (n mult of 1024) =======================
__global__ void cvt_bf16(const float* __restrict__ in, ushort* __restrict__ out) {
    int i = blockIdx.x * 256 + threadIdx.x;
    float4 v = *(const float4*)(in + (size_t)i * 4);
    uint32_t lo = (uint32_t)f2b(v.x) | ((uint32_t)f2b(v.y) << 16);
    uint32_t hi = (uint32_t)f2b(v.z) | ((uint32_t)f2b(v.w) << 16);
    *(uint2*)(out + (size_t)i * 4) = make_uint2(lo, hi);
}

// ============ rmsnorm f32 in -> bf16 out =====================================
__global__ __launch_bounds__(256) void rmsnorm_b(const float* __restrict__ in, int istride,
                                                 ushort* __restrict__ out, int ostride,
                                                 const float* __restrict__ w, int L) {
    int row = blockIdx.x, tid = threadIdx.x;
    const float* xr = in + (size_t)row * istride;
    ushort* yr = out + (size_t)row * ostride;
    __shared__ float red[256];
    float ss = 0.f;
    for (int i = tid; i < L; i += 256) { float v = xr[i]; ss += v * v; }
    red[tid] = ss; __syncthreads();
    for (int st = 128; st > 0; st >>= 1) {
        if (tid < st) red[tid] += red[tid + st];
        __syncthreads();
    }
    float scale = rsqrtf(red[0] / (float)L + 1e-6f);
    for (int i = tid; i < L; i += 256) yr[i] = f2b(xr[i] * scale * w[i]);
}

// ============ rope q (interleaved, dims 128..191) + scale -> qb[NH][S][192] ==
__global__ void rope_q_b(const float* __restrict__ qf, ushort* __restrict__ qb,
                         const float* __restrict__ cosb, const float* __restrict__ sinb) {
    int idx = blockIdx.x * 256 + threadIdx.x;  // S*NH*96
    int p = idx % 96, h = (idx / 96) & 15, t = idx / (96 * 16);
    const float sc = 0.07216878364870322f;  // 192^-0.5 folded into Q
    const float* src = qf + (size_t)t * 3072 + h * 192;
    ushort* dst = qb + ((size_t)h * S + t) * 192;
    if (p < 64) {
        dst[2 * p]     = f2b(src[2 * p] * sc);
        dst[2 * p + 1] = f2b(src[2 * p + 1] * sc);
    } else {
        int j = p - 64;
        float c = cosb[t * 32 + j], s = sinb[t * 32 + j];
        float xr = src[128 + 2 * j], xi = src[128 + 2 * j + 1];
        dst[128 + 2 * j]     = f2b((xr * c - xi * s) * sc);
        dst[128 + 2 * j + 1] = f2b((xr * s + xi * c) * sc);
    }
}

// ============ rope k_pe: kvf[:,512:576] -> kpe[S,64] f32 =====================
__global__ void rope_kpe_kernel(const float* __restrict__ kvf, float* __restrict__ kpe,
                                const float* __restrict__ cosb, const float* __restrict__ sinb) {
    int idx = blockIdx.x * 256 + threadIdx.x;  // S*32
    int j = idx & 31, t = idx >> 5;
    float c = cosb[t * 32 + j], s = sinb[t * 32 + j];
    const float* p = kvf + (size_t)t * (KVL + DR) + KVL + 2 * j;
    float xr = p[0], xi = p[1];
    kpe[t * 64 + 2 * j] = xr * c - xi * s;
    kpe[t * 64 + 2 * j + 1] = xr * s + xi * c;
}

// ============ build kb[NH][S][192] bf16 from kvexp + kpe =====================
__global__ void build_kb(const float* __restrict__ kvexp, const float* __restrict__ kpe,
                         ushort* __restrict__ kb) {
    int idx = blockIdx.x * 256 + threadIdx.x;  // NH*S*192
    int d = idx % 192, s = (idx / 192) & 2047, h = idx / (192 * 2048);
    float v = (d < 128) ? kvexp[(size_t)s * 4096 + h * 256 + d] : kpe[s * 64 + (d - 128)];
    kb[idx] = f2b(v);
}

// ============ vT[NH][128][S] bf16 = transpose of kvexp V part ================
__global__ __launch_bounds__(256) void vtrans(const float* __restrict__ kvexp, ushort* __restrict__ vT) {
    __shared__ float t[64][65];
    int s0 = blockIdx.x * 64, d0 = blockIdx.y * 64, h = blockIdx.z;
    int rr = threadIdx.x >> 6, cc = threadIdx.x & 63;
#pragma unroll
    for (int p = 0; p < 16; p++)
        t[p * 4 + rr][cc] = kvexp[(size_t)(s0 + p * 4 + rr) * 4096 + h * 256 + 128 + d0 + cc];
    __syncthreads();
#pragma unroll
    for (int p = 0; p < 16; p++)
        vT[((size_t)h * 128 + d0 + p * 4 + rr) * S + s0 + cc] = f2b(t[cc][p * 4 + rr]);
}

// ============ rope non-interleaved on qi first 64 dims (qi: [S,4,128] f32) ===
__global__ void rope_qi_kernel(float* __restrict__ qi, const float* __restrict__ cosb,
                               const float* __restrict__ sinb) {
    int idx = blockIdx.x * 256 + threadIdx.x;  // S*4*32
    int j = idx & 31, h = (idx >> 5) & 3, t = idx >> 7;
    float c = cosb[t * 32 + j], s = sinb[t * 32 + j];
    float* p = qi + ((size_t)t * IH + h) * ID;
    float x1 = p[j], x2 = p[j + 32];
    p[j] = x1 * c - x2 * s;
    p[j + 32] = x1 * s + x2 * c;
}

// ============ layernorm + rope (non-interleaved, first 64) on ki rows ========
__global__ __launch_bounds__(128) void ki_ln_rope_kernel(float* __restrict__ ki,
                                                         const float* __restrict__ g,
                                                         const float* __restrict__ bb,
                                                         const float* __restrict__ cosb,
                                                         const float* __restrict__ sinb) {
    int t = blockIdx.x, tid = threadIdx.x;
    float* p = ki + (size_t)t * ID;
    __shared__ float s1[128], s2m[128];
    float v = p[tid];
    s1[tid] = v; s2m[tid] = v * v; __syncthreads();
    for (int st = 64; st > 0; st >>= 1) {
        if (tid < st) { s1[tid] += s1[tid + st]; s2m[tid] += s2m[tid + st]; }
        __syncthreads();
    }
    float mu = s1[0] / 128.f;
    float var = s2m[0] / 128.f - mu * mu;
    float y = (v - mu) * rsqrtf(var + 1e-6f) * g[tid] + bb[tid];
    __syncthreads();
    s1[tid] = y; __syncthreads();
    if (tid >= 64) {
        p[tid] = y;
    } else if (tid < 32) {
        float c = cosb[t * 32 + tid], s = sinb[t * 32 + tid];
        float x1 = s1[tid], x2 = s1[tid + 32];
        p[tid] = x1 * c - x2 * s;
        p[tid + 32] = x1 * s + x2 * c;
    }
}

// ============ transpose ki [S,128] -> kiT [128,S] ============================
__global__ void transpose_ki_kernel(const float* __restrict__ ki, float* __restrict__ kiT) {
    int idx = blockIdx.x * 256 + threadIdx.x;  // S*128
    int t = idx >> 7, d = idx & 127;
    kiT[(size_t)d * S + t] = ki[idx];
}

// ============ iw[t][j] = x[t] . IWproj[:,j] ==================================
__global__ __launch_bounds__(256) void iw_kernel(const float* __restrict__ x,
                                                 const float* __restrict__ IWproj,
                                                 float* __restrict__ iw) {
    int t = blockIdx.x, tid = threadIdx.x;
    __shared__ float red[256];
    float p0 = 0.f, p1 = 0.f, p2 = 0.f, p3 = 0.f;
    for (int k = tid; k < HID; k += 256) {
        float a = x[(size_t)t * HID + k];
        const float* wr = IWproj + k * 4;
        p0 += a * wr[0]; p1 += a * wr[1]; p2 += a * wr[2]; p3 += a * wr[3];
    }
#pragma unroll
    for (int j = 0; j < 4; j++) {
        float v = (j == 0) ? p0 : (j == 1) ? p1 : (j == 2) ? p2 : p3;
        red[tid] = v; __syncthreads();
        for (int st = 128; st > 0; st >>= 1) {
            if (tid < st) red[tid] += red[tid + st];
            __syncthreads();
        }
        if (tid == 0) iw[t * 4 + j] = red[0];
        __syncthreads();
    }
}

// ============ indexer score (fp32, 4 cols/thread, causal region only) ========
__global__ __launch_bounds__(256) void iscore4(const float* __restrict__ qi,
                                               const float* __restrict__ kiT,
                                               const float* __restrict__ iw,
                                               float* __restrict__ iscore) {
    int t = blockIdx.x;
    int s0 = blockIdx.y * 1024;
    if (s0 > t) return;               // uniform early-out
    int s = s0 + threadIdx.x * 4;
    __shared__ float qs[4 * ID];
    __shared__ float ws4[4];
    for (int i = threadIdx.x; i < 4 * ID; i += 256) qs[i] = qi[(size_t)t * (4 * ID) + i];
    if (threadIdx.x < 4) ws4[threadIdx.x] = iw[t * 4 + threadIdx.x] * 0.04419417382415922f;
    __syncthreads();
    if (s > t) return;
    float a[4][4];
#pragma unroll
    for (int h = 0; h < 4; h++)
#pragma unroll
        for (int c = 0; c < 4; c++) a[h][c] = 0.f;
    for (int d = 0; d < ID; d++) {
        float4 kv = *(const float4*)(kiT + (size_t)d * S + s);
#pragma unroll
        for (int h = 0; h < 4; h++) {
            float qv = qs[h * ID + d];
            a[h][0] += qv * kv.x; a[h][1] += qv * kv.y;
            a[h][2] += qv * kv.z; a[h][3] += qv * kv.w;
        }
    }
#pragma unroll
    for (int c = 0; c < 4; c++) {
        if (s + c > t) break;
        float sc = fmaxf(a[0][c], 0.f) * ws4[0] + fmaxf(a[1][c], 0.f) * ws4[1] +
                   fmaxf(a[2][c], 0.f) * ws4[2] + fmaxf(a[3][c], 0.f) * ws4[3];
        iscore[(size_t)t * S + s + c] = sc;
    }
}

// ============ exact top-k -> bitmask (registers-resident radix select) =======
__device__ inline unsigned sortable_u32(float f) {
    unsigned u = __float_as_uint(f);
    return (u & 0x80000000u) ? ~u : (u | 0x80000000u);
}

__global__ __launch_bounds__(256) void topk_mask(const float* __restrict__ iscore,
                                                 uint32_t* __restrict__ msk) {
    int t = blockIdx.x, tid = threadIdx.x;
    uint32_t* mrow = msk + (size_t)t * 64;
    if (t < TOPK) {                        // all causal keys kept
        if (tid < 64) {
            int full = (t + 1) >> 5;
            uint32_t wv = (tid < full) ? 0xFFFFFFFFu : 0u;
            if (tid == full) { int rem = (t + 1) & 31; wv = rem ? ((1u << rem) - 1u) : 0u; }
            mrow[tid] = wv;
        }
        return;
    }
    const float* row = iscore + (size_t)t * S;
    const int n = t + 1;
    const int wv = tid >> 6;
    __shared__ int hist[4][256];
    __shared__ int scan[256];
    __shared__ int bsel, ksel;
    __shared__ uint32_t bytes[256];

    int jb = tid * 8;
    float4 v0 = *(const float4*)(row + jb);
    float4 v1 = *(const float4*)(row + jb + 4);
    uint32_t lsu[8];
    {
        float vvv[8] = {v0.x, v0.y, v0.z, v0.w, v1.x, v1.y, v1.z, v1.w};
#pragma unroll
        for (int i = 0; i < 8; i++)
            lsu[i] = (jb + i < n) ? sortable_u32(vvv[i]) : 0u;
    }
    unsigned prefix = 0, prefmask = 0;
    int k = TOPK;
    for (int pass = 0; pass < 4; pass++) {
        int shift = 24 - pass * 8;
#pragma unroll
        for (int r = 0; r < 4; r++) hist[r][tid] = 0;
        __syncthreads();
#pragma unroll
        for (int i = 0; i < 8; i++) {
            uint32_t u = lsu[i];
            if ((u & prefmask) == prefix) atomicAdd(&hist[wv][(u >> shift) & 255], 1);
        }
        __syncthreads();
        int h = hist[0][tid] + hist[1][tid] + hist[2][tid] + hist[3][tid];
        scan[tid] = h; __syncthreads();
        for (int st = 1; st < 256; st <<= 1) {
            int a = scan[tid];
            int b = (tid + st < 256) ? scan[tid + st] : 0;
            __syncthreads();
            scan[tid] = a + b;
            __syncthreads();
        }
        int snext = (tid < 255) ? scan[tid + 1] : 0;
        if (scan[tid] >= k && snext < k) { bsel = tid; ksel = k - snext; }
        __syncthreads();
        prefix |= ((unsigned)bsel) << shift;
        prefmask |= 0xFFu << shift;
        k = ksel;
        __syncthreads();
    }
    const unsigned u_thr = prefix;
    const int need = k;
    uint32_t gtbits = 0, eqbits = 0;
    int eqcnt = 0;
#pragma unroll
    for (int i = 0; i < 8; i++) {
        uint32_t u = lsu[i];
        if (u > u_thr) gtbits |= 1u << i;
        else if (u == u_thr) { eqbits |= 1u << i; eqcnt++; }
    }
    scan[tid] = eqcnt; __syncthreads();
    for (int st = 1; st < 256; st <<= 1) {
        int a = scan[tid];
        int b = (tid >= st) ? scan[tid - st] : 0;
        __syncthreads();
        scan[tid] = a + b;
        __syncthreads();
    }
    int room = need - (scan[tid] - eqcnt);
    uint32_t keep = 0;
#pragma unroll
    for (int i = 0; i < 8; i++)
        if ((eqbits >> i) & 1u) { if (room > 0) { keep |= 1u << i; room--; } }
    bytes[tid] = gtbits | keep;
    __syncthreads();
    if (tid < 64)
        mrow[tid] = bytes[tid * 4] | (bytes[tid * 4 + 1] << 8) |
                    (bytes[tid * 4 + 2] << 16) | (bytes[tid * 4 + 3] << 24);
}

// ============ balanced masked flash attention v2 =============================
// Block handles q-tiles ta=blockIdx.x and tb=31-ta (constant 33 k-tile visits).
// In-register online softmax via quad shuffles; wave-private Pm (no barrier).
__global__ __launch_bounds__(256, 2) void fattn2(const ushort* __restrict__ qb,
                                                 const ushort* __restrict__ kb,
                                                 const ushort* __restrict__ vT,
                                                 const uint32_t* __restrict__ msk,
                                                 ushort* __restrict__ attn_b) {
    __shared__ ushort Ks[64 * 200];     // K tile [64 keys][192] pad->200
    __shared__ ushort Vs[128 * 72];     // V^T tile [128 d][64 keys] pad->72
    __shared__ ushort Pm[4][16 * 72];   // per-wave P transpose buffers
    const int tid = threadIdx.x;
    const int w = tid >> 6, l = tid & 63, quad = l >> 4, lane = l & 15;
    const int h = blockIdx.y;
    const int ta = blockIdx.x, tb = 31 - ta;
    const int qa0 = ta * 64, qb0 = tb * 64;

    bf16x8 qfa[6], qfb[6];
    {
        const ushort* qpa = qb + ((size_t)h * S + qa0 + w * 16 + lane) * 192;
        const ushort* qpb = qb + ((size_t)h * S + qb0 + w * 16 + lane) * 192;
#pragma unroll
        for (int ks = 0; ks < 6; ks++) {
            qfa[ks] = *(const bf16x8*)(qpa + ks * 32 + quad * 8);
            qfb[ks] = *(const bf16x8*)(qpb + ks * 32 + quad * 8);
        }
    }
    f32x4 oa[8], ob[8];
#pragma unroll
    for (int i = 0; i < 8; i++) { oa[i] = (f32x4)0.f; ob[i] = (f32x4)0.f; }
    float ma[4], la[4], mb[4], lb[4];
#pragma unroll
    for (int r = 0; r < 4; r++) { ma[r] = -1e30f; la[r] = 0.f; mb[r] = -1e30f; lb[r] = 0.f; }

    ushort* pw = &Pm[w][0];

    for (int kt = 0; kt <= tb; kt++) {
        const int s0 = kt * 64;
        __syncthreads();
        {   // stage K tile
            const ushort* src = kb + ((size_t)h * S + s0 + (tid >> 2)) * 192;
            ushort* dst = Ks + (tid >> 2) * 200;
#pragma unroll
            for (int i = 0; i < 6; i++) {
                int c = (tid & 3) + 4 * i;
                *(uint4*)(dst + c * 8) = *(const uint4*)(src + c * 8);
            }
        }
        {   // stage V^T tile
            const ushort* src = vT + ((size_t)h * 128 + (tid >> 1)) * S + s0;
            ushort* dst = Vs + (tid >> 1) * 72;
#pragma unroll
            for (int i = 0; i < 4; i++) {
                int c = (tid & 1) + 2 * i;
                *(uint4*)(dst + c * 8) = *(const uint4*)(src + c * 8);
            }
        }
        __syncthreads();

#pragma unroll
        for (int pass = 0; pass < 2; pass++) {
            if (pass == 0 && kt > ta) continue;
            const bf16x8* qf = (pass == 0) ? qfa : qfb;
            f32x4* oacc      = (pass == 0) ? oa : ob;
            float* mm        = (pass == 0) ? ma : mb;
            float* ll        = (pass == 0) ? la : lb;
            const int q0t    = (pass == 0) ? qa0 : qb0;

            // QK^T
            f32x4 sc[4];
#pragma unroll
            for (int kq = 0; kq < 4; kq++) {
                sc[kq] = (f32x4)0.f;
#pragma unroll
                for (int ks = 0; ks < 6; ks++) {
                    bf16x8 bfr = *(const bf16x8*)(Ks + (kq * 16 + lane) * 200 + ks * 32 + quad * 8);
                    sc[kq] = __builtin_amdgcn_mfma_f32_16x16x32_bf16(qf[ks], bfr, sc[kq], 0, 0, 0);
                }
            }
            // mask words (uniform across lane16 -> broadcast loads)
            uint32_t w0[4], w1[4];
            {
                const int rowbase = q0t + w * 16 + quad * 4;
#pragma unroll
                for (int r = 0; r < 4; r++) {
                    const uint32_t* mp = msk + (size_t)(rowbase + r) * 64 + (s0 >> 5);
                    w0[r] = mp[0]; w1[r] = mp[1];
                }
            }
            // apply mask, row max (in-register, quad-local shuffle reduce)
            float vmax[4] = {-1e30f, -1e30f, -1e30f, -1e30f};
#pragma unroll
            for (int kq = 0; kq < 4; kq++) {
                const int sh = (kq & 1) * 16 + lane;
#pragma unroll
                for (int r = 0; r < 4; r++) {
                    uint32_t word = (kq < 2) ? w0[r] : w1[r];
                    float v = ((word >> sh) & 1u) ? sc[kq][r] : -1e30f;
                    sc[kq][r] = v;
                    vmax[r] = fmaxf(vmax[r], v);
                }
            }
#pragma unroll
            for (int off = 1; off < 16; off <<= 1)
#pragma unroll
                for (int r = 0; r < 4; r++)
                    vmax[r] = fmaxf(vmax[r], __shfl_xor(vmax[r], off, 64));
            float alpha[4], psum[4];
#pragma unroll
            for (int r = 0; r < 4; r++) {
                float mnew = fmaxf(mm[r], vmax[r]);
                alpha[r] = __expf(mm[r] - mnew);
                mm[r] = mnew;
                psum[r] = 0.f;
            }
            // exp + write P to wave-private LDS (transpose for A-frag)
#pragma unroll
            for (int kq = 0; kq < 4; kq++)
#pragma unroll
                for (int r = 0; r < 4; r++) {
                    float v = sc[kq][r];
                    float e = (v < -1e29f) ? 0.f : __expf(v - mm[r]);
                    psum[r] += e;
                    pw[(quad * 4 + r) * 72 + kq * 16 + lane] = f2b(e);
                }
#pragma unroll
            for (int off = 1; off < 16; off <<= 1)
#pragma unroll
                for (int r = 0; r < 4; r++)
                    psum[r] += __shfl_xor(psum[r], off, 64);
#pragma unroll
            for (int r = 0; r < 4; r++) ll[r] = ll[r] * alpha[r] + psum[r];

            // PV: A-frag from wave-private Pm (wave-internal lgkm ordering)
            bf16x8 pfr[2];
#pragma unroll
            for (int k2 = 0; k2 < 2; k2++)
                pfr[k2] = *(const bf16x8*)(pw + lane * 72 + k2 * 32 + quad * 8);
#pragma unroll
            for (int nt = 0; nt < 8; nt++) {
#pragma unroll
                for (int r = 0; r < 4; r++) oacc[nt][r] *= alpha[r];
#pragma unroll
                for (int k2 = 0; k2 < 2; k2++) {
                    bf16x8 vfr = *(const bf16x8*)(Vs + (nt * 16 + lane) * 72 + k2 * 32 + quad * 8);
                    oacc[nt] = __builtin_amdgcn_mfma_f32_16x16x32_bf16(pfr[k2], vfr, oacc[nt], 0, 0, 0);
                }
            }
        }
    }
    // epilogue: both tiles
#pragma unroll
    for (int pass = 0; pass < 2; pass++) {
        const f32x4* oacc = (pass == 0) ? oa : ob;
        const float* ll   = (pass == 0) ? la : lb;
        const int q0t     = (pass == 0) ? qa0 : qb0;
        float inv[4];
#pragma unroll
        for (int r = 0; r < 4; r++) inv[r] = 1.f / ll[r];
#pragma unroll
        for (int nt = 0; nt < 8; nt++)
#pragma unroll
            for (int r = 0; r < 4; r++) {
                int row = q0t + w * 16 + quad * 4 + r;
                attn_b[(size_t)row * 2048 + h * 128 + nt * 16 + lane] = f2b(oacc[nt][r] * inv[r]);
            }
    }
}

// ============ host ===========================================================
extern "C" void kernel_launch(void* const* d_in, const int* in_sizes, int n_in,
                              void* d_out, int out_size, void* d_ws, size_t ws_size,
                              hipStream_t stream) {
    const float* x        = (const float*)d_in[0];
    const float* cosb     = (const float*)d_in[1];
    const float* sinb     = (const float*)d_in[2];
    const float* Wq_a     = (const float*)d_in[4];
    const float* q_norm_w = (const float*)d_in[5];
    const float* Wq_b     = (const float*)d_in[6];
    const float* Wkv_a    = (const float*)d_in[7];
    const float* kv_norm_w= (const float*)d_in[8];
    const float* Wkv_b    = (const float*)d_in[9];
    const float* Wo       = (const float*)d_in[10];
    const float* IWq_b    = (const float*)d_in[11];
    const float* IWk      = (const float*)d_in[12];
    const float* Ik_norm_w= (const float*)d_in[13];
    const float* Ik_norm_b= (const float*)d_in[14];
    const float* IWproj   = (const float*)d_in[15];
    float* out = (float*)d_out;

    char* ws = (char*)d_ws;
    size_t o = 0;
    auto take = [&](size_t b) { char* p = ws + o; o += (b + 255) & ~(size_t)255; return p; };
    ushort* xb     = (ushort*)take((size_t)S * HID * 2);
    ushort* qrb    = (ushort*)take((size_t)S * QL * 2);
    ushort* qb     = (ushort*)take((size_t)NH * S * DQ * 2);
    ushort* kvnb   = (ushort*)take((size_t)S * KVL * 2);
    float*  kpe    = (float*)take((size_t)S * DR * 4);
    ushort* kb     = (ushort*)take((size_t)NH * S * DQ * 2);
    ushort* vT     = (ushort*)take((size_t)NH * DV * S * 2);
    float*  iw     = (float*)take((size_t)S * IH * 4);
    uint32_t* msk  = (uint32_t*)take((size_t)S * 64 * 4);
    ushort* poolw  = (ushort*)take((size_t)3072 * 1536 * 2);       // largest WT
    char*   poola  = take((size_t)33554432);                       // f32 activation pool
    char*   poolb  = take((size_t)16777216);                       // iscore / attn_b

    float* qr_f   = (float*)poola;             // [S][QL]
    float* qf_f   = (float*)poola;             // [S][3072]
    float* kvf_f  = (float*)poola;             // [S][576]
    float* kvexp  = (float*)poola;             // [S][4096]
    float* qi     = (float*)poola;             // [S][512]   (after kvexp dead)
    float* ki     = (float*)(poola + 4194304); // [S][128]
    float* kiT    = (float*)(poola + 5242880); // [128][S]
    float* iscore = (float*)poolb;             // [S][S]
    ushort* attn_b = (ushort*)poolb;           // [S][2048] (after topk consumed iscore)

    // --- x -> bf16
    cvt_bf16<<<(S * HID) / 1024, 256, 0, stream>>>(x, xb);

    // --- qr = rmsnorm(x @ Wq_a)
    wtrans<<<dim3(CDIV(HID, 64), CDIV(QL, 64)), 256, 0, stream>>>(Wq_a, poolw, HID, QL);
    gemm_bt<<<dim3(QL / 128, S / 128), 256, 0, stream>>>(xb, poolw, qr_f, S, QL, HID);
    rmsnorm_b<<<S, 256, 0, stream>>>(qr_f, QL, qrb, QL, q_norm_w, QL);

    // --- q = qr @ Wq_b ; rope+scale -> qb bf16 [NH][S][192]
    wtrans<<<dim3(CDIV(QL, 64), CDIV(NH * DQ, 64)), 256, 0, stream>>>(Wq_b, poolw, QL, NH * DQ);
    gemm_bt<<<dim3((NH * DQ) / 128, S / 128), 256, 0, stream>>>(qrb, poolw, qf_f, S, NH * DQ, QL);
    rope_q_b<<<(S * NH * 96) / 256, 256, 0, stream>>>(qf_f, qb, cosb, sinb);

    // --- kv_full = x @ Wkv_a ; norm + rope
    wtrans<<<dim3(CDIV(HID, 64), CDIV(KVL + DR, 64)), 256, 0, stream>>>(Wkv_a, poolw, HID, KVL + DR);
    gemm_bt<<<dim3(CDIV(KVL + DR, 128), S / 128), 256, 0, stream>>>(xb, poolw, kvf_f, S, KVL + DR, HID);
    rmsnorm_b<<<S, 256, 0, stream>>>(kvf_f, KVL + DR, kvnb, KVL, kv_norm_w, KVL);
    rope_kpe_kernel<<<(S * 32) / 256, 256, 0, stream>>>(kvf_f, kpe, cosb, sinb);

    // --- kv_exp = kvn @ Wkv_b ; build kb / vT
    wtrans<<<dim3(CDIV(KVL, 64), CDIV(NH * (DN + DV), 64)), 256, 0, stream>>>(Wkv_b, poolw, KVL, NH * (DN + DV));
    gemm_bt<<<dim3((NH * (DN + DV)) / 128, S / 128), 256, 0, stream>>>(kvnb, poolw, kvexp, S, NH * (DN + DV), KVL);
    build_kb<<<(NH * S * DQ) / 256, 256, 0, stream>>>(kvexp, kpe, kb);
    vtrans<<<dim3(S / 64, DV / 64, NH), 256, 0, stream>>>(kvexp, vT);

    // --- indexer inputs (fp32 precision-sensitive path)
    wtrans<<<dim3(CDIV(QL, 64), CDIV(IH * ID, 64)), 256, 0, stream>>>(IWq_b, poolw, QL, IH * ID);
    gemm_bt<<<dim3((IH * ID) / 128, S / 128), 256, 0, stream>>>(qrb, poolw, qi, S, IH * ID, QL);
    rope_qi_kernel<<<(S * IH * 32) / 256, 256, 0, stream>>>(qi, cosb, sinb);
    wtrans<<<dim3(CDIV(HID, 64), CDIV(ID, 64)), 256, 0, stream>>>(IWk, poolw, HID, ID);
    gemm_bt<<<dim3(ID / 128, S / 128), 256, 0, stream>>>(xb, poolw, ki, S, ID, HID);
    ki_ln_rope_kernel<<<S, 128, 0, stream>>>(ki, Ik_norm_w, Ik_norm_b, cosb, sinb);
    iw_kernel<<<S, 256, 0, stream>>>(x, IWproj, iw);
    transpose_ki_kernel<<<(S * ID) / 256, 256, 0, stream>>>(ki, kiT);

    // --- indexer scores + exact top-k -> bitmap
    iscore4<<<dim3(S, S / 1024), 256, 0, stream>>>(qi, kiT, iw, iscore);
    topk_mask<<<S, 256, 0, stream>>>(iscore, msk);

    // --- balanced masked flash attention
    fattn2<<<dim3(16, NH), 256, 0, stream>>>(qb, kb, vT, msk, attn_b);

    // --- out = attn @ Wo
    wtrans<<<dim3(CDIV(NH * DV, 64), CDIV(HID, 64)), 256, 0, stream>>>(Wo, poolw, NH * DV, HID);
    gemm_bt<<<dim3(HID / 128, S / 128), 256, 0, stream>>>(attn_b, poolw, out, S, HID, NH * DV);

    (void)in_sizes; (void)n_in; (void)out_size; (void)ws_size; (void)o;
}

// Round 5
// 637.064 us; speedup vs baseline: 9.9813x; 1.0993x over previous
//
#include <hip/hip_runtime.h>
#include <math.h>
#include <stdint.h>

#define S 2048
#define HID 2048
#define NH 16
#define QL 1536
#define KVL 512
#define DN 128
#define DR 64
#define DV 128
#define DQ 192
#define IH 4
#define ID 128
#define TOPK 1024

#define CDIV(a,b) (((a)+(b)-1)/(b))

typedef float f32x4 __attribute__((ext_vector_type(4)));
typedef short bf16x8 __attribute__((ext_vector_type(8)));

__device__ __forceinline__ ushort f2b(float f) {
    uint32_t u = __float_as_uint(f);
    u += 0x7fffu + ((u >> 16) & 1u);
    return (ushort)(u >> 16);
}

#define GLL16(g, l)                                                            \
    __builtin_amdgcn_global_load_lds(                                          \
        (const __attribute__((address_space(1))) void*)(g),                    \
        (__attribute__((address_space(3))) void*)(l), 16, 0, 0)

// ============ bf16 MFMA GEMM (m97-style): C[M,N]f32 = A[M,K] @ BT[N,K] ======
__global__ __launch_bounds__(256) void gemm_bt(const ushort* __restrict__ A,
                                               const ushort* __restrict__ BT,
                                               float* __restrict__ C,
                                               int M, int N, int K) {
    __shared__ ushort As[128 * 32];   // unpadded: lane-ordered DMA layout
    __shared__ ushort Bs[128 * 32];
    const int tid = threadIdx.x;
    const int w = tid >> 6, l = tid & 63;
    const int quad = l >> 4, lane = l & 15;
    const int row0 = blockIdx.y * 128, col0 = blockIdx.x * 128;
    const int wr = (w >> 1) * 64, wc = (w & 1) * 64;
    f32x4 acc[4][4];
#pragma unroll
    for (int i = 0; i < 4; i++)
#pragma unroll
        for (int j = 0; j < 4; j++) acc[i][j] = (f32x4)0.f;

    const int srow = w * 32 + (l >> 2);
    const int c8 = (l & 3) * 8;
    const ushort* pa0 = A + (size_t)(row0 + srow) * K + c8;
    const ushort* pa1 = A + (size_t)(row0 + srow + 16) * K + c8;
    int bn0 = col0 + srow;      if (bn0 > N - 1) bn0 = N - 1;
    int bn1 = col0 + srow + 16; if (bn1 > N - 1) bn1 = N - 1;
    const ushort* pb0 = BT + (size_t)bn0 * K + c8;
    const ushort* pb1 = BT + (size_t)bn1 * K + c8;
    ushort* sa0 = As + srow * 32 + c8;
    ushort* sa1 = sa0 + 16 * 32;
    ushort* sb0 = Bs + srow * 32 + c8;
    ushort* sb1 = sb0 + 16 * 32;

    for (int k0 = 0; k0 < K; k0 += 32) {
        __syncthreads();
        GLL16(pa0 + k0, sa0);
        GLL16(pa1 + k0, sa1);
        GLL16(pb0 + k0, sb0);
        GLL16(pb1 + k0, sb1);
        __syncthreads();
        bf16x8 af[4], bf[4];
#pragma unroll
        for (int mi = 0; mi < 4; mi++)
            af[mi] = *(const bf16x8*)(As + (wr + mi * 16 + lane) * 32 + quad * 8);
#pragma unroll
        for (int ni = 0; ni < 4; ni++)
            bf[ni] = *(const bf16x8*)(Bs + (wc + ni * 16 + lane) * 32 + quad * 8);
#pragma unroll
        for (int mi = 0; mi < 4; mi++)
#pragma unroll
            for (int ni = 0; ni < 4; ni++)
                acc[mi][ni] = __builtin_amdgcn_mfma_f32_16x16x32_bf16(af[mi], bf[ni], acc[mi][ni], 0, 0, 0);
    }
#pragma unroll
    for (int mi = 0; mi < 4; mi++)
#pragma unroll
        for (int ni = 0; ni < 4; ni++)
#pragma unroll
            for (int r = 0; r < 4; r++) {
                int row = row0 + wr + mi * 16 + quad * 4 + r;
                int col = col0 + wc + ni * 16 + lane;
                if (col < N) C[(size_t)row * N + col] = acc[mi][ni][r];
            }
}

// ============ 64x64-tile variant for small N (more blocks) ===================
__global__ __launch_bounds__(256) void gemm_bt64(const ushort* __restrict__ A,
                                                 const ushort* __restrict__ BT,
                                                 float* __restrict__ C,
                                                 int M, int N, int K) {
    __shared__ ushort As[64 * 32];
    __shared__ ushort Bs[64 * 32];
    const int tid = threadIdx.x;
    const int w = tid >> 6, l = tid & 63;
    const int quad = l >> 4, lane = l & 15;
    const int row0 = blockIdx.y * 64, col0 = blockIdx.x * 64;
    f32x4 acc[4];
#pragma unroll
    for (int j = 0; j < 4; j++) acc[j] = (f32x4)0.f;

    const int srow = tid >> 2;          // 0..63
    const int c8 = (tid & 3) * 8;
    const ushort* pa = A + (size_t)(row0 + srow) * K + c8;
    int bn = col0 + srow; if (bn > N - 1) bn = N - 1;
    const ushort* pb = BT + (size_t)bn * K + c8;
    ushort* sa = As + srow * 32 + c8;
    ushort* sb = Bs + srow * 32 + c8;

    for (int k0 = 0; k0 < K; k0 += 32) {
        __syncthreads();
        GLL16(pa + k0, sa);
        GLL16(pb + k0, sb);
        __syncthreads();
        bf16x8 af = *(const bf16x8*)(As + (w * 16 + lane) * 32 + quad * 8);
#pragma unroll
        for (int ni = 0; ni < 4; ni++) {
            bf16x8 bf = *(const bf16x8*)(Bs + (ni * 16 + lane) * 32 + quad * 8);
            acc[ni] = __builtin_amdgcn_mfma_f32_16x16x32_bf16(af, bf, acc[ni], 0, 0, 0);
        }
    }
#pragma unroll
    for (int ni = 0; ni < 4; ni++)
#pragma unroll
        for (int r = 0; r < 4; r++) {
            int row = row0 + w * 16 + quad * 4 + r;
            int col = col0 + ni * 16 + lane;
            if (col < N) C[(size_t)row * N + col] = acc[ni][r];
        }
}

// ============ weight transpose+convert: W[K,N]f32 -> WT[N,K]bf16 =============
__global__ __launch_bounds__(256) void wtrans(const float* __restrict__ W, ushort* __restrict__ WT,
                                              int K, int N) {
    __shared__ float t[64][65];
    int k0 = blockIdx.x * 64, n0 = blockIdx.y * 64;
    int rr = threadIdx.x >> 6, cc = threadIdx.x & 63;
#pragma unroll
    for (int p = 0; p < 16; p++) {
        int k = k0 + p * 4 + rr, n = n0 + cc;
        t[p * 4 + rr][cc] = (k < K && n < N) ? W[(size_t)k * N + n] : 0.f;
    }
    __syncthreads();
#pragma unroll
    for (int p = 0; p < 16; p++) {
        int n = n0 + p * 4 + rr, k = k0 + cc;
        if (n < N && k < K) WT[(size_t)n * K + k] = f2b(t[cc][p * 4 + rr]);
    }
}

// ============ elementwise f32 -> bf16 (n mult of 1024) =======================
__global__ void cvt_bf16(const float* __restrict__ in, ushort* __restrict__ out) {
    int i = blockIdx.x * 256 + threadIdx.x;
    float4 v = *(const float4*)(in + (size_t)i * 4);
    uint32_t lo = (uint32_t)f2b(v.x) | ((uint32_t)f2b(v.y) << 16);
    uint32_t hi = (uint32_t)f2b(v.z) | ((uint32_t)f2b(v.w) << 16);
    *(uint2*)(out + (size_t)i * 4) = make_uint2(lo, hi);
}

// ============ rmsnorm f32 in -> bf16 out =====================================
__global__ __launch_bounds__(256) void rmsnorm_b(const float* __restrict__ in, int istride,
                                                 ushort* __restrict__ out, int ostride,
                                                 const float* __restrict__ w, int L) {
    int row = blockIdx.x, tid = threadIdx.x;
    const float* xr = in + (size_t)row * istride;
    ushort* yr = out + (size_t)row * ostride;
    __shared__ float red[256];
    float ss = 0.f;
    for (int i = tid; i < L; i += 256) { float v = xr[i]; ss += v * v; }
    red[tid] = ss; __syncthreads();
    for (int st = 128; st > 0; st >>= 1) {
        if (tid < st) red[tid] += red[tid + st];
        __syncthreads();
    }
    float scale = rsqrtf(red[0] / (float)L + 1e-6f);
    for (int i = tid; i < L; i += 256) yr[i] = f2b(xr[i] * scale * w[i]);
}

// ============ rope q (interleaved, dims 128..191) + scale -> qb[NH][S][192] ==
__global__ void rope_q_b(const float* __restrict__ qf, ushort* __restrict__ qb,
                         const float* __restrict__ cosb, const float* __restrict__ sinb) {
    int idx = blockIdx.x * 256 + threadIdx.x;  // S*NH*96
    int p = idx % 96, h = (idx / 96) & 15, t = idx / (96 * 16);
    const float sc = 0.07216878364870322f;  // 192^-0.5 folded into Q
    const float* src = qf + (size_t)t * 3072 + h * 192;
    ushort* dst = qb + ((size_t)h * S + t) * 192;
    if (p < 64) {
        dst[2 * p]     = f2b(src[2 * p] * sc);
        dst[2 * p + 1] = f2b(src[2 * p + 1] * sc);
    } else {
        int j = p - 64;
        float c = cosb[t * 32 + j], s = sinb[t * 32 + j];
        float xr = src[128 + 2 * j], xi = src[128 + 2 * j + 1];
        dst[128 + 2 * j]     = f2b((xr * c - xi * s) * sc);
        dst[128 + 2 * j + 1] = f2b((xr * s + xi * c) * sc);
    }
}

// ============ rope k_pe: kvf[:,512:576] -> kpe[S,64] f32 =====================
__global__ void rope_kpe_kernel(const float* __restrict__ kvf, float* __restrict__ kpe,
                                const float* __restrict__ cosb, const float* __restrict__ sinb) {
    int idx = blockIdx.x * 256 + threadIdx.x;  // S*32
    int j = idx & 31, t = idx >> 5;
    float c = cosb[t * 32 + j], s = sinb[t * 32 + j];
    const float* p = kvf + (size_t)t * (KVL + DR) + KVL + 2 * j;
    float xr = p[0], xi = p[1];
    kpe[t * 64 + 2 * j] = xr * c - xi * s;
    kpe[t * 64 + 2 * j + 1] = xr * s + xi * c;
}

// ============ build kb[NH][S][192] bf16 from kvexp + kpe =====================
__global__ void build_kb(const float* __restrict__ kvexp, const float* __restrict__ kpe,
                         ushort* __restrict__ kb) {
    int idx = blockIdx.x * 256 + threadIdx.x;  // NH*S*192
    int d = idx % 192, s = (idx / 192) & 2047, h = idx / (192 * 2048);
    float v = (d < 128) ? kvexp[(size_t)s * 4096 + h * 256 + d] : kpe[s * 64 + (d - 128)];
    kb[idx] = f2b(v);
}

// ============ vT[NH][128][S] bf16 = transpose of kvexp V part ================
__global__ __launch_bounds__(256) void vtrans(const float* __restrict__ kvexp, ushort* __restrict__ vT) {
    __shared__ float t[64][65];
    int s0 = blockIdx.x * 64, d0 = blockIdx.y * 64, h = blockIdx.z;
    int rr = threadIdx.x >> 6, cc = threadIdx.x & 63;
#pragma unroll
    for (int p = 0; p < 16; p++)
        t[p * 4 + rr][cc] = kvexp[(size_t)(s0 + p * 4 + rr) * 4096 + h * 256 + 128 + d0 + cc];
    __syncthreads();
#pragma unroll
    for (int p = 0; p < 16; p++)
        vT[((size_t)h * 128 + d0 + p * 4 + rr) * S + s0 + cc] = f2b(t[cc][p * 4 + rr]);
}

// ============ rope non-interleaved on qi first 64 dims (qi: [S,4,128] f32) ===
__global__ void rope_qi_kernel(float* __restrict__ qi, const float* __restrict__ cosb,
                               const float* __restrict__ sinb) {
    int idx = blockIdx.x * 256 + threadIdx.x;  // S*4*32
    int j = idx & 31, h = (idx >> 5) & 3, t = idx >> 7;
    float c = cosb[t * 32 + j], s = sinb[t * 32 + j];
    float* p = qi + ((size_t)t * IH + h) * ID;
    float x1 = p[j], x2 = p[j + 32];
    p[j] = x1 * c - x2 * s;
    p[j + 32] = x1 * s + x2 * c;
}

// ============ layernorm + rope (non-interleaved, first 64) on ki rows ========
__global__ __launch_bounds__(128) void ki_ln_rope_kernel(float* __restrict__ ki,
                                                         const float* __restrict__ g,
                                                         const float* __restrict__ bb,
                                                         const float* __restrict__ cosb,
                                                         const float* __restrict__ sinb) {
    int t = blockIdx.x, tid = threadIdx.x;
    float* p = ki + (size_t)t * ID;
    __shared__ float s1[128], s2m[128];
    float v = p[tid];
    s1[tid] = v; s2m[tid] = v * v; __syncthreads();
    for (int st = 64; st > 0; st >>= 1) {
        if (tid < st) { s1[tid] += s1[tid + st]; s2m[tid] += s2m[tid + st]; }
        __syncthreads();
    }
    float mu = s1[0] / 128.f;
    float var = s2m[0] / 128.f - mu * mu;
    float y = (v - mu) * rsqrtf(var + 1e-6f) * g[tid] + bb[tid];
    __syncthreads();
    s1[tid] = y; __syncthreads();
    if (tid >= 64) {
        p[tid] = y;
    } else if (tid < 32) {
        float c = cosb[t * 32 + tid], s = sinb[t * 32 + tid];
        float x1 = s1[tid], x2 = s1[tid + 32];
        p[tid] = x1 * c - x2 * s;
        p[tid + 32] = x1 * s + x2 * c;
    }
}

// ============ transpose ki [S,128] -> kiT [128,S] ============================
__global__ void transpose_ki_kernel(const float* __restrict__ ki, float* __restrict__ kiT) {
    int idx = blockIdx.x * 256 + threadIdx.x;  // S*128
    int t = idx >> 7, d = idx & 127;
    kiT[(size_t)d * S + t] = ki[idx];
}

// ============ iw[t][j] = x[t] . IWproj[:,j] ==================================
__global__ __launch_bounds__(256) void iw_kernel(const float* __restrict__ x,
                                                 const float* __restrict__ IWproj,
                                                 float* __restrict__ iw) {
    int t = blockIdx.x, tid = threadIdx.x;
    __shared__ float red[256];
    float p0 = 0.f, p1 = 0.f, p2 = 0.f, p3 = 0.f;
    for (int k = tid; k < HID; k += 256) {
        float a = x[(size_t)t * HID + k];
        const float* wr = IWproj + k * 4;
        p0 += a * wr[0]; p1 += a * wr[1]; p2 += a * wr[2]; p3 += a * wr[3];
    }
#pragma unroll
    for (int j = 0; j < 4; j++) {
        float v = (j == 0) ? p0 : (j == 1) ? p1 : (j == 2) ? p2 : p3;
        red[tid] = v; __syncthreads();
        for (int st = 128; st > 0; st >>= 1) {
            if (tid < st) red[tid] += red[tid + st];
            __syncthreads();
        }
        if (tid == 0) iw[t * 4 + j] = red[0];
        __syncthreads();
    }
}

// ============ indexer score (fp32, 4 cols/thread, causal region only) ========
__global__ __launch_bounds__(256) void iscore4(const float* __restrict__ qi,
                                               const float* __restrict__ kiT,
                                               const float* __restrict__ iw,
                                               float* __restrict__ iscore) {
    int t = blockIdx.x;
    int s0 = blockIdx.y * 1024;
    if (s0 > t) return;               // uniform early-out
    int s = s0 + threadIdx.x * 4;
    __shared__ float qs[4 * ID];
    __shared__ float ws4[4];
    for (int i = threadIdx.x; i < 4 * ID; i += 256) qs[i] = qi[(size_t)t * (4 * ID) + i];
    if (threadIdx.x < 4) ws4[threadIdx.x] = iw[t * 4 + threadIdx.x] * 0.04419417382415922f;
    __syncthreads();
    if (s > t) return;
    float a[4][4];
#pragma unroll
    for (int h = 0; h < 4; h++)
#pragma unroll
        for (int c = 0; c < 4; c++) a[h][c] = 0.f;
    for (int d = 0; d < ID; d++) {
        float4 kv = *(const float4*)(kiT + (size_t)d * S + s);
#pragma unroll
        for (int h = 0; h < 4; h++) {
            float qv = qs[h * ID + d];
            a[h][0] += qv * kv.x; a[h][1] += qv * kv.y;
            a[h][2] += qv * kv.z; a[h][3] += qv * kv.w;
        }
    }
#pragma unroll
    for (int c = 0; c < 4; c++) {
        if (s + c > t) break;
        float sc = fmaxf(a[0][c], 0.f) * ws4[0] + fmaxf(a[1][c], 0.f) * ws4[1] +
                   fmaxf(a[2][c], 0.f) * ws4[2] + fmaxf(a[3][c], 0.f) * ws4[3];
        iscore[(size_t)t * S + s + c] = sc;
    }
}

// ============ exact top-k -> bitmask (registers-resident radix select) =======
__device__ inline unsigned sortable_u32(float f) {
    unsigned u = __float_as_uint(f);
    return (u & 0x80000000u) ? ~u : (u | 0x80000000u);
}

__global__ __launch_bounds__(256) void topk_mask(const float* __restrict__ iscore,
                                                 uint32_t* __restrict__ msk) {
    int t = blockIdx.x, tid = threadIdx.x;
    uint32_t* mrow = msk + (size_t)t * 64;
    if (t < TOPK) {                        // all causal keys kept
        if (tid < 64) {
            int full = (t + 1) >> 5;
            uint32_t wv2 = (tid < full) ? 0xFFFFFFFFu : 0u;
            if (tid == full) { int rem = (t + 1) & 31; wv2 = rem ? ((1u << rem) - 1u) : 0u; }
            mrow[tid] = wv2;
        }
        return;
    }
    const float* row = iscore + (size_t)t * S;
    const int n = t + 1;
    const int wv = tid >> 6;
    __shared__ int hist[4][256];
    __shared__ int scan[256];
    __shared__ int bsel, ksel;
    __shared__ uint32_t bytes[256];

    int jb = tid * 8;
    float4 v0 = *(const float4*)(row + jb);
    float4 v1 = *(const float4*)(row + jb + 4);
    uint32_t lsu[8];
    {
        float vvv[8] = {v0.x, v0.y, v0.z, v0.w, v1.x, v1.y, v1.z, v1.w};
#pragma unroll
        for (int i = 0; i < 8; i++)
            lsu[i] = (jb + i < n) ? sortable_u32(vvv[i]) : 0u;
    }
    unsigned prefix = 0, prefmask = 0;
    int k = TOPK;
    for (int pass = 0; pass < 4; pass++) {
        int shift = 24 - pass * 8;
#pragma unroll
        for (int r = 0; r < 4; r++) hist[r][tid] = 0;
        __syncthreads();
#pragma unroll
        for (int i = 0; i < 8; i++) {
            uint32_t u = lsu[i];
            if ((u & prefmask) == prefix) atomicAdd(&hist[wv][(u >> shift) & 255], 1);
        }
        __syncthreads();
        int h = hist[0][tid] + hist[1][tid] + hist[2][tid] + hist[3][tid];
        scan[tid] = h; __syncthreads();
        for (int st = 1; st < 256; st <<= 1) {
            int a = scan[tid];
            int b = (tid + st < 256) ? scan[tid + st] : 0;
            __syncthreads();
            scan[tid] = a + b;
            __syncthreads();
        }
        int snext = (tid < 255) ? scan[tid + 1] : 0;
        if (scan[tid] >= k && snext < k) { bsel = tid; ksel = k - snext; }
        __syncthreads();
        prefix |= ((unsigned)bsel) << shift;
        prefmask |= 0xFFu << shift;
        k = ksel;
        __syncthreads();
    }
    const unsigned u_thr = prefix;
    const int need = k;
    uint32_t gtbits = 0, eqbits = 0;
    int eqcnt = 0;
#pragma unroll
    for (int i = 0; i < 8; i++) {
        uint32_t u = lsu[i];
        if (u > u_thr) gtbits |= 1u << i;
        else if (u == u_thr) { eqbits |= 1u << i; eqcnt++; }
    }
    scan[tid] = eqcnt; __syncthreads();
    for (int st = 1; st < 256; st <<= 1) {
        int a = scan[tid];
        int b = (tid >= st) ? scan[tid - st] : 0;
        __syncthreads();
        scan[tid] = a + b;
        __syncthreads();
    }
    int room = need - (scan[tid] - eqcnt);
    uint32_t keep = 0;
#pragma unroll
    for (int i = 0; i < 8; i++)
        if ((eqbits >> i) & 1u) { if (room > 0) { keep |= 1u << i; room--; } }
    bytes[tid] = gtbits | keep;
    __syncthreads();
    if (tid < 64)
        mrow[tid] = bytes[tid * 4] | (bytes[tid * 4 + 1] << 8) |
                    (bytes[tid * 4 + 2] << 16) | (bytes[tid * 4 + 3] << 24);
}

// ============ split-K balanced masked flash attention v3 =====================
// 512 blocks (1D). Decode: r=b&7, j=b>>3, head=r+8*(j&1) -> head h on XCD h%8
// (2 heads/XCD -> K/V L2-resident). idx=j>>1: pair=idx&15, part=idx>>4.
// Pair (ta=pair, tb=31-pair) has 33 tile-visits; part0 takes visits [0,17),
// part1 [17,33). Partials (O f32, m, l) merged by attn_combine.
__global__ __launch_bounds__(256, 2) void fattn3(const ushort* __restrict__ qb,
                                                 const ushort* __restrict__ kb,
                                                 const ushort* __restrict__ vT,
                                                 const uint32_t* __restrict__ msk,
                                                 float* __restrict__ Opart,
                                                 float* __restrict__ mlbuf) {
    __shared__ ushort Ks[64 * 200];
    __shared__ ushort Vs[128 * 72];
    __shared__ ushort Pm[4][16 * 72];
    const int tid = threadIdx.x;
    const int w = tid >> 6, l = tid & 63, quad = l >> 4, lane = l & 15;
    const int b = blockIdx.x;
    const int r8 = b & 7, j = b >> 3;
    const int h = r8 + 8 * (j & 1);
    const int idx = j >> 1;
    const int pair = idx & 15, part = idx >> 4;
    const int ta = pair, tb = 31 - pair, nA = ta + 1;
    const int vlo = part ? 17 : 0, vhi = part ? 33 : 17;
    const int qa0 = ta * 64, qb0 = tb * 64;

    bf16x8 qfa[6], qfb[6];
    {
        const ushort* qpa = qb + ((size_t)h * S + qa0 + w * 16 + lane) * 192;
        const ushort* qpb = qb + ((size_t)h * S + qb0 + w * 16 + lane) * 192;
#pragma unroll
        for (int ks = 0; ks < 6; ks++) {
            qfa[ks] = *(const bf16x8*)(qpa + ks * 32 + quad * 8);
            qfb[ks] = *(const bf16x8*)(qpb + ks * 32 + quad * 8);
        }
    }
    f32x4 oa[8], ob[8];
#pragma unroll
    for (int i = 0; i < 8; i++) { oa[i] = (f32x4)0.f; ob[i] = (f32x4)0.f; }
    float ma[4], la[4], mb[4], lb[4];
#pragma unroll
    for (int r = 0; r < 4; r++) { ma[r] = -1e30f; la[r] = 0.f; mb[r] = -1e30f; lb[r] = 0.f; }

    ushort* pw = &Pm[w][0];

    for (int kt = 0; kt <= tb; kt++) {
        const int idxB = (kt <= ta) ? 2 * kt : kt + nA;
        const int hasA = (kt <= ta);
        const int idxA = 2 * kt + 1;
        const bool doB = (idxB >= vlo && idxB < vhi);
        const bool doA = hasA && (idxA >= vlo && idxA < vhi);
        if (!(doA || doB)) continue;           // block-uniform
        const int s0 = kt * 64;
        __syncthreads();
        {   // stage K tile
            const ushort* src = kb + ((size_t)h * S + s0 + (tid >> 2)) * 192;
            ushort* dst = Ks + (tid >> 2) * 200;
#pragma unroll
            for (int i = 0; i < 6; i++) {
                int c = (tid & 3) + 4 * i;
                *(uint4*)(dst + c * 8) = *(const uint4*)(src + c * 8);
            }
        }
        {   // stage V^T tile
            const ushort* src = vT + ((size_t)h * 128 + (tid >> 1)) * S + s0;
            ushort* dst = Vs + (tid >> 1) * 72;
#pragma unroll
            for (int i = 0; i < 4; i++) {
                int c = (tid & 1) + 2 * i;
                *(uint4*)(dst + c * 8) = *(const uint4*)(src + c * 8);
            }
        }
        __syncthreads();

#pragma unroll
        for (int pass = 0; pass < 2; pass++) {
            if (pass == 0 && !doA) continue;
            if (pass == 1 && !doB) continue;
            const bf16x8* qf = (pass == 0) ? qfa : qfb;
            f32x4* oacc      = (pass == 0) ? oa : ob;
            float* mm        = (pass == 0) ? ma : mb;
            float* ll        = (pass == 0) ? la : lb;
            const int q0t    = (pass == 0) ? qa0 : qb0;

            // QK^T
            f32x4 sc[4];
#pragma unroll
            for (int kq = 0; kq < 4; kq++) {
                sc[kq] = (f32x4)0.f;
#pragma unroll
                for (int ks = 0; ks < 6; ks++) {
                    bf16x8 bfr = *(const bf16x8*)(Ks + (kq * 16 + lane) * 200 + ks * 32 + quad * 8);
                    sc[kq] = __builtin_amdgcn_mfma_f32_16x16x32_bf16(qf[ks], bfr, sc[kq], 0, 0, 0);
                }
            }
            // mask words
            uint32_t w0[4], w1[4];
            {
                const int rowbase = q0t + w * 16 + quad * 4;
#pragma unroll
                for (int r = 0; r < 4; r++) {
                    const uint32_t* mp = msk + (size_t)(rowbase + r) * 64 + (s0 >> 5);
                    w0[r] = mp[0]; w1[r] = mp[1];
                }
            }
            float vmax[4] = {-1e30f, -1e30f, -1e30f, -1e30f};
#pragma unroll
            for (int kq = 0; kq < 4; kq++) {
                const int sh = (kq & 1) * 16 + lane;
#pragma unroll
                for (int r = 0; r < 4; r++) {
                    uint32_t word = (kq < 2) ? w0[r] : w1[r];
                    float v = ((word >> sh) & 1u) ? sc[kq][r] : -1e30f;
                    sc[kq][r] = v;
                    vmax[r] = fmaxf(vmax[r], v);
                }
            }
#pragma unroll
            for (int off = 1; off < 16; off <<= 1)
#pragma unroll
                for (int r = 0; r < 4; r++)
                    vmax[r] = fmaxf(vmax[r], __shfl_xor(vmax[r], off, 64));
            float alpha[4], psum[4];
#pragma unroll
            for (int r = 0; r < 4; r++) {
                float mnew = fmaxf(mm[r], vmax[r]);
                alpha[r] = __expf(mm[r] - mnew);
                mm[r] = mnew;
                psum[r] = 0.f;
            }
#pragma unroll
            for (int kq = 0; kq < 4; kq++)
#pragma unroll
                for (int r = 0; r < 4; r++) {
                    float v = sc[kq][r];
                    float e = (v < -1e29f) ? 0.f : __expf(v - mm[r]);
                    psum[r] += e;
                    pw[(quad * 4 + r) * 72 + kq * 16 + lane] = f2b(e);
                }
#pragma unroll
            for (int off = 1; off < 16; off <<= 1)
#pragma unroll
                for (int r = 0; r < 4; r++)
                    psum[r] += __shfl_xor(psum[r], off, 64);
#pragma unroll
            for (int r = 0; r < 4; r++) ll[r] = ll[r] * alpha[r] + psum[r];

            bf16x8 pfr[2];
#pragma unroll
            for (int k2 = 0; k2 < 2; k2++)
                pfr[k2] = *(const bf16x8*)(pw + lane * 72 + k2 * 32 + quad * 8);
#pragma unroll
            for (int nt = 0; nt < 8; nt++) {
#pragma unroll
                for (int r = 0; r < 4; r++) oacc[nt][r] *= alpha[r];
#pragma unroll
                for (int k2 = 0; k2 < 2; k2++) {
                    bf16x8 vfr = *(const bf16x8*)(Vs + (nt * 16 + lane) * 72 + k2 * 32 + quad * 8);
                    oacc[nt] = __builtin_amdgcn_mfma_f32_16x16x32_bf16(pfr[k2], vfr, oacc[nt], 0, 0, 0);
                }
            }
        }
    }
    // epilogue: write f32 partials (unnormalized O + m,l) for both q-tiles
#pragma unroll
    for (int pass = 0; pass < 2; pass++) {
        const f32x4* oacc = (pass == 0) ? oa : ob;
        const float* mm   = (pass == 0) ? ma : mb;
        const float* ll   = (pass == 0) ? la : lb;
        const int qt      = (pass == 0) ? ta : tb;
        float* Op = Opart + (size_t)(((qt * 16 + h) * 2) + part) * (64 * 128);
        float* mlp = mlbuf + (size_t)(((qt * 16 + h) * 2) + part) * 128;
#pragma unroll
        for (int nt = 0; nt < 8; nt++)
#pragma unroll
            for (int r = 0; r < 4; r++)
                Op[(w * 16 + quad * 4 + r) * 128 + nt * 16 + lane] = oacc[nt][r];
        if (lane == 0) {
#pragma unroll
            for (int r = 0; r < 4; r++) {
                mlp[(w * 16 + quad * 4 + r) * 2 + 0] = mm[r];
                mlp[(w * 16 + quad * 4 + r) * 2 + 1] = ll[r];
            }
        }
    }
}

// ============ combine split-K partials -> attn_b bf16 ========================
__global__ __launch_bounds__(256) void attn_combine(const float* __restrict__ Opart,
                                                    const float* __restrict__ mlbuf,
                                                    ushort* __restrict__ attn_b) {
    const int qt = blockIdx.x, h = blockIdx.y, tid = threadIdx.x;
    const size_t base = ((size_t)qt * 16 + h) * 2;
    const float* Op0 = Opart + base * (64 * 128);
    const float* Op1 = Op0 + 64 * 128;
    const float* ml0 = mlbuf + base * 128;
    const float* ml1 = ml0 + 128;
#pragma unroll
    for (int i = 0; i < 32; i++) {
        int id = tid + i * 256;
        int row = id >> 7, d = id & 127;
        float m0 = ml0[row * 2], l0 = ml0[row * 2 + 1];
        float m1 = ml1[row * 2], l1 = ml1[row * 2 + 1];
        float m = fmaxf(m0, m1);
        float e0 = __expf(m0 - m), e1 = __expf(m1 - m);
        float linv = 1.f / (l0 * e0 + l1 * e1);
        float v = (Op0[id] * e0 + Op1[id] * e1) * linv;
        attn_b[(size_t)(qt * 64 + row) * 2048 + h * 128 + d] = f2b(v);
    }
}

// ============ host ===========================================================
extern "C" void kernel_launch(void* const* d_in, const int* in_sizes, int n_in,
                              void* d_out, int out_size, void* d_ws, size_t ws_size,
                              hipStream_t stream) {
    const float* x        = (const float*)d_in[0];
    const float* cosb     = (const float*)d_in[1];
    const float* sinb     = (const float*)d_in[2];
    const float* Wq_a     = (const float*)d_in[4];
    const float* q_norm_w = (const float*)d_in[5];
    const float* Wq_b     = (const float*)d_in[6];
    const float* Wkv_a    = (const float*)d_in[7];
    const float* kv_norm_w= (const float*)d_in[8];
    const float* Wkv_b    = (const float*)d_in[9];
    const float* Wo       = (const float*)d_in[10];
    const float* IWq_b    = (const float*)d_in[11];
    const float* IWk      = (const float*)d_in[12];
    const float* Ik_norm_w= (const float*)d_in[13];
    const float* Ik_norm_b= (const float*)d_in[14];
    const float* IWproj   = (const float*)d_in[15];
    float* out = (float*)d_out;

    char* ws = (char*)d_ws;
    size_t o = 0;
    auto take = [&](size_t b) { char* p = ws + o; o += (b + 255) & ~(size_t)255; return p; };
    ushort* xb     = (ushort*)take((size_t)S * HID * 2);
    ushort* qrb    = (ushort*)take((size_t)S * QL * 2);
    ushort* qb     = (ushort*)take((size_t)NH * S * DQ * 2);
    ushort* kvnb   = (ushort*)take((size_t)S * KVL * 2);
    float*  kpe    = (float*)take((size_t)S * DR * 4);
    ushort* kb     = (ushort*)take((size_t)NH * S * DQ * 2);
    ushort* vT     = (ushort*)take((size_t)NH * DV * S * 2);
    float*  iw     = (float*)take((size_t)S * IH * 4);
    uint32_t* msk  = (uint32_t*)take((size_t)S * 64 * 4);
    float*  mlbuf  = (float*)take((size_t)32 * 16 * 2 * 64 * 2 * 4);   // 512 KB
    ushort* poolw  = (ushort*)take((size_t)3072 * 1536 * 2);       // largest WT
    char*   poola  = take((size_t)33554432);                       // f32 activation pool
    char*   poolb  = take((size_t)16777216);                       // iscore / attn_b

    float* qr_f   = (float*)poola;             // [S][QL]
    float* qf_f   = (float*)poola;             // [S][3072]
    float* kvf_f  = (float*)poola;             // [S][576]
    float* kvexp  = (float*)poola;             // [S][4096]
    float* qi     = (float*)poola;             // [S][512]   (after kvexp dead)
    float* ki     = (float*)(poola + 4194304); // [S][128]
    float* kiT    = (float*)(poola + 5242880); // [128][S]
    float* Opart  = (float*)poola;             // [32][16][2][64][128] f32 (after indexer dead)
    float* iscore = (float*)poolb;             // [S][S]
    ushort* attn_b = (ushort*)poolb;           // [S][2048] (after topk consumed iscore)

    // --- x -> bf16
    cvt_bf16<<<(S * HID) / 1024, 256, 0, stream>>>(x, xb);

    // --- qr = rmsnorm(x @ Wq_a)
    wtrans<<<dim3(CDIV(HID, 64), CDIV(QL, 64)), 256, 0, stream>>>(Wq_a, poolw, HID, QL);
    gemm_bt<<<dim3(QL / 128, S / 128), 256, 0, stream>>>(xb, poolw, qr_f, S, QL, HID);
    rmsnorm_b<<<S, 256, 0, stream>>>(qr_f, QL, qrb, QL, q_norm_w, QL);

    // --- q = qr @ Wq_b ; rope+scale -> qb bf16 [NH][S][192]
    wtrans<<<dim3(CDIV(QL, 64), CDIV(NH * DQ, 64)), 256, 0, stream>>>(Wq_b, poolw, QL, NH * DQ);
    gemm_bt<<<dim3((NH * DQ) / 128, S / 128), 256, 0, stream>>>(qrb, poolw, qf_f, S, NH * DQ, QL);
    rope_q_b<<<(S * NH * 96) / 256, 256, 0, stream>>>(qf_f, qb, cosb, sinb);

    // --- kv_full = x @ Wkv_a ; norm + rope
    wtrans<<<dim3(CDIV(HID, 64), CDIV(KVL + DR, 64)), 256, 0, stream>>>(Wkv_a, poolw, HID, KVL + DR);
    gemm_bt64<<<dim3(CDIV(KVL + DR, 64), S / 64), 256, 0, stream>>>(xb, poolw, kvf_f, S, KVL + DR, HID);
    rmsnorm_b<<<S, 256, 0, stream>>>(kvf_f, KVL + DR, kvnb, KVL, kv_norm_w, KVL);
    rope_kpe_kernel<<<(S * 32) / 256, 256, 0, stream>>>(kvf_f, kpe, cosb, sinb);

    // --- kv_exp = kvn @ Wkv_b ; build kb / vT
    wtrans<<<dim3(CDIV(KVL, 64), CDIV(NH * (DN + DV), 64)), 256, 0, stream>>>(Wkv_b, poolw, KVL, NH * (DN + DV));
    gemm_bt<<<dim3((NH * (DN + DV)) / 128, S / 128), 256, 0, stream>>>(kvnb, poolw, kvexp, S, NH * (DN + DV), KVL);
    build_kb<<<(NH * S * DQ) / 256, 256, 0, stream>>>(kvexp, kpe, kb);
    vtrans<<<dim3(S / 64, DV / 64, NH), 256, 0, stream>>>(kvexp, vT);

    // --- indexer inputs (fp32 precision-sensitive path)
    wtrans<<<dim3(CDIV(QL, 64), CDIV(IH * ID, 64)), 256, 0, stream>>>(IWq_b, poolw, QL, IH * ID);
    gemm_bt64<<<dim3((IH * ID) / 64, S / 64), 256, 0, stream>>>(qrb, poolw, qi, S, IH * ID, QL);
    rope_qi_kernel<<<(S * IH * 32) / 256, 256, 0, stream>>>(qi, cosb, sinb);
    wtrans<<<dim3(CDIV(HID, 64), CDIV(ID, 64)), 256, 0, stream>>>(IWk, poolw, HID, ID);
    gemm_bt64<<<dim3(ID / 64, S / 64), 256, 0, stream>>>(xb, poolw, ki, S, ID, HID);
    ki_ln_rope_kernel<<<S, 128, 0, stream>>>(ki, Ik_norm_w, Ik_norm_b, cosb, sinb);
    iw_kernel<<<S, 256, 0, stream>>>(x, IWproj, iw);
    transpose_ki_kernel<<<(S * ID) / 256, 256, 0, stream>>>(ki, kiT);

    // --- indexer scores + exact top-k -> bitmap
    iscore4<<<dim3(S, S / 1024), 256, 0, stream>>>(qi, kiT, iw, iscore);
    topk_mask<<<S, 256, 0, stream>>>(iscore, msk);

    // --- split-K balanced masked flash attention + combine
    fattn3<<<512, 256, 0, stream>>>(qb, kb, vT, msk, Opart, mlbuf);
    attn_combine<<<dim3(32, 16), 256, 0, stream>>>(Opart, mlbuf, attn_b);

    // --- out = attn @ Wo
    wtrans<<<dim3(CDIV(NH * DV, 64), CDIV(HID, 64)), 256, 0, stream>>>(Wo, poolw, NH * DV, HID);
    gemm_bt<<<dim3(HID / 128, S / 128), 256, 0, stream>>>(attn_b, poolw, out, S, HID, NH * DV);

    (void)in_sizes; (void)n_in; (void)out_size; (void)ws_size; (void)o;
}

// Round 6
// 551.693 us; speedup vs baseline: 11.5258x; 1.1547x over previous
//
#include <hip/hip_runtime.h>
#include <math.h>
#include <stdint.h>

#define S 2048
#define HID 2048
#define NH 16
#define QL 1536
#define KVL 512
#define DN 128
#define DR 64
#define DV 128
#define DQ 192
#define IH 4
#define ID 128
#define TOPK 1024

#define N1 2244   // Wq_a(1536) | Wkv_a(576) | IWk(128) | IWproj(4)
#define N2 3584   // Wq_b(3072) | IWq_b(512)

#define CDIV(a,b) (((a)+(b)-1)/(b))

typedef float f32x4 __attribute__((ext_vector_type(4)));
typedef short bf16x8 __attribute__((ext_vector_type(8)));

__device__ __forceinline__ ushort f2b(float f) {
    uint32_t u = __float_as_uint(f);
    u += 0x7fffu + ((u >> 16) & 1u);
    return (ushort)(u >> 16);
}

#define GLL16(g, l)                                                            \
    __builtin_amdgcn_global_load_lds(                                          \
        (const __attribute__((address_space(1))) void*)(g),                    \
        (__attribute__((address_space(3))) void*)(l), 16, 0, 0)

// ============ bf16 MFMA GEMM: C[M,N]f32 = A[M,K] @ BT[N,K] ===================
__global__ __launch_bounds__(256) void gemm_bt(const ushort* __restrict__ A,
                                               const ushort* __restrict__ BT,
                                               float* __restrict__ C,
                                               int M, int N, int K) {
    __shared__ ushort As[128 * 32];
    __shared__ ushort Bs[128 * 32];
    const int tid = threadIdx.x;
    const int w = tid >> 6, l = tid & 63;
    const int quad = l >> 4, lane = l & 15;
    const int row0 = blockIdx.y * 128, col0 = blockIdx.x * 128;
    const int wr = (w >> 1) * 64, wc = (w & 1) * 64;
    f32x4 acc[4][4];
#pragma unroll
    for (int i = 0; i < 4; i++)
#pragma unroll
        for (int j = 0; j < 4; j++) acc[i][j] = (f32x4)0.f;

    const int srow = w * 32 + (l >> 2);
    const int c8 = (l & 3) * 8;
    const ushort* pa0 = A + (size_t)(row0 + srow) * K + c8;
    const ushort* pa1 = A + (size_t)(row0 + srow + 16) * K + c8;
    int bn0 = col0 + srow;      if (bn0 > N - 1) bn0 = N - 1;
    int bn1 = col0 + srow + 16; if (bn1 > N - 1) bn1 = N - 1;
    const ushort* pb0 = BT + (size_t)bn0 * K + c8;
    const ushort* pb1 = BT + (size_t)bn1 * K + c8;
    ushort* sa0 = As + srow * 32 + c8;
    ushort* sa1 = sa0 + 16 * 32;
    ushort* sb0 = Bs + srow * 32 + c8;
    ushort* sb1 = sb0 + 16 * 32;

    for (int k0 = 0; k0 < K; k0 += 32) {
        __syncthreads();
        GLL16(pa0 + k0, sa0);
        GLL16(pa1 + k0, sa1);
        GLL16(pb0 + k0, sb0);
        GLL16(pb1 + k0, sb1);
        __syncthreads();
        bf16x8 af[4], bf[4];
#pragma unroll
        for (int mi = 0; mi < 4; mi++)
            af[mi] = *(const bf16x8*)(As + (wr + mi * 16 + lane) * 32 + quad * 8);
#pragma unroll
        for (int ni = 0; ni < 4; ni++)
            bf[ni] = *(const bf16x8*)(Bs + (wc + ni * 16 + lane) * 32 + quad * 8);
#pragma unroll
        for (int mi = 0; mi < 4; mi++)
#pragma unroll
            for (int ni = 0; ni < 4; ni++)
                acc[mi][ni] = __builtin_amdgcn_mfma_f32_16x16x32_bf16(af[mi], bf[ni], acc[mi][ni], 0, 0, 0);
    }
#pragma unroll
    for (int mi = 0; mi < 4; mi++)
#pragma unroll
        for (int ni = 0; ni < 4; ni++)
#pragma unroll
            for (int r = 0; r < 4; r++) {
                int row = row0 + wr + mi * 16 + quad * 4 + r;
                int col = col0 + wc + ni * 16 + lane;
                if (col < N) C[(size_t)row * N + col] = acc[mi][ni][r];
            }
}

// ============ same GEMM, bf16 output (for kvexp) =============================
__global__ __launch_bounds__(256) void gemm_bt_h(const ushort* __restrict__ A,
                                                 const ushort* __restrict__ BT,
                                                 ushort* __restrict__ C,
                                                 int M, int N, int K) {
    __shared__ ushort As[128 * 32];
    __shared__ ushort Bs[128 * 32];
    const int tid = threadIdx.x;
    const int w = tid >> 6, l = tid & 63;
    const int quad = l >> 4, lane = l & 15;
    const int row0 = blockIdx.y * 128, col0 = blockIdx.x * 128;
    const int wr = (w >> 1) * 64, wc = (w & 1) * 64;
    f32x4 acc[4][4];
#pragma unroll
    for (int i = 0; i < 4; i++)
#pragma unroll
        for (int j = 0; j < 4; j++) acc[i][j] = (f32x4)0.f;

    const int srow = w * 32 + (l >> 2);
    const int c8 = (l & 3) * 8;
    const ushort* pa0 = A + (size_t)(row0 + srow) * K + c8;
    const ushort* pa1 = A + (size_t)(row0 + srow + 16) * K + c8;
    int bn0 = col0 + srow;      if (bn0 > N - 1) bn0 = N - 1;
    int bn1 = col0 + srow + 16; if (bn1 > N - 1) bn1 = N - 1;
    const ushort* pb0 = BT + (size_t)bn0 * K + c8;
    const ushort* pb1 = BT + (size_t)bn1 * K + c8;
    ushort* sa0 = As + srow * 32 + c8;
    ushort* sa1 = sa0 + 16 * 32;
    ushort* sb0 = Bs + srow * 32 + c8;
    ushort* sb1 = sb0 + 16 * 32;

    for (int k0 = 0; k0 < K; k0 += 32) {
        __syncthreads();
        GLL16(pa0 + k0, sa0);
        GLL16(pa1 + k0, sa1);
        GLL16(pb0 + k0, sb0);
        GLL16(pb1 + k0, sb1);
        __syncthreads();
        bf16x8 af[4], bf[4];
#pragma unroll
        for (int mi = 0; mi < 4; mi++)
            af[mi] = *(const bf16x8*)(As + (wr + mi * 16 + lane) * 32 + quad * 8);
#pragma unroll
        for (int ni = 0; ni < 4; ni++)
            bf[ni] = *(const bf16x8*)(Bs + (wc + ni * 16 + lane) * 32 + quad * 8);
#pragma unroll
        for (int mi = 0; mi < 4; mi++)
#pragma unroll
            for (int ni = 0; ni < 4; ni++)
                acc[mi][ni] = __builtin_amdgcn_mfma_f32_16x16x32_bf16(af[mi], bf[ni], acc[mi][ni], 0, 0, 0);
    }
#pragma unroll
    for (int mi = 0; mi < 4; mi++)
#pragma unroll
        for (int ni = 0; ni < 4; ni++)
#pragma unroll
            for (int r = 0; r < 4; r++) {
                int row = row0 + wr + mi * 16 + quad * 4 + r;
                int col = col0 + wc + ni * 16 + lane;
                if (col < N) C[(size_t)row * N + col] = f2b(acc[mi][ni][r]);
            }
}

// ============ weight transpose+convert: W[K,N]f32 -> WT[N,K]bf16 =============
__global__ __launch_bounds__(256) void wtrans(const float* __restrict__ W, ushort* __restrict__ WT,
                                              int K, int N) {
    __shared__ float t[64][65];
    int k0 = blockIdx.x * 64, n0 = blockIdx.y * 64;
    int rr = threadIdx.x >> 6, cc = threadIdx.x & 63;
#pragma unroll
    for (int p = 0; p < 16; p++) {
        int k = k0 + p * 4 + rr, n = n0 + cc;
        t[p * 4 + rr][cc] = (k < K && n < N) ? W[(size_t)k * N + n] : 0.f;
    }
    __syncthreads();
#pragma unroll
    for (int p = 0; p < 16; p++) {
        int n = n0 + p * 4 + rr, k = k0 + cc;
        if (n < N && k < K) WT[(size_t)n * K + k] = f2b(t[cc][p * 4 + rr]);
    }
}

// ============ elementwise f32 -> bf16 (n mult of 1024) =======================
__global__ void cvt_bf16(const float* __restrict__ in, ushort* __restrict__ out) {
    int i = blockIdx.x * 256 + threadIdx.x;
    float4 v = *(const float4*)(in + (size_t)i * 4);
    uint32_t lo = (uint32_t)f2b(v.x) | ((uint32_t)f2b(v.y) << 16);
    uint32_t hi = (uint32_t)f2b(v.z) | ((uint32_t)f2b(v.w) << 16);
    *(uint2*)(out + (size_t)i * 4) = make_uint2(lo, hi);
}

// ============ rmsnorm f32 in -> bf16 out (strided in) ========================
__global__ __launch_bounds__(256) void rmsnorm_b(const float* __restrict__ in, int istride,
                                                 ushort* __restrict__ out, int ostride,
                                                 const float* __restrict__ w, int L) {
    int row = blockIdx.x, tid = threadIdx.x;
    const float* xr = in + (size_t)row * istride;
    ushort* yr = out + (size_t)row * ostride;
    __shared__ float red[256];
    float ss = 0.f;
    for (int i = tid; i < L; i += 256) { float v = xr[i]; ss += v * v; }
    red[tid] = ss; __syncthreads();
    for (int st = 128; st > 0; st >>= 1) {
        if (tid < st) red[tid] += red[tid + st];
        __syncthreads();
    }
    float scale = rsqrtf(red[0] / (float)L + 1e-6f);
    for (int i = tid; i < L; i += 256) yr[i] = f2b(xr[i] * scale * w[i]);
}

// ============ rope q (interleaved, dims 128..191) + scale -> qb[NH][S][192] ==
__global__ void rope_q_b(const float* __restrict__ qf, ushort* __restrict__ qb,
                         const float* __restrict__ cosb, const float* __restrict__ sinb) {
    int idx = blockIdx.x * 256 + threadIdx.x;  // S*NH*96
    int p = idx % 96, h = (idx / 96) & 15, t = idx / (96 * 16);
    const float sc = 0.07216878364870322f;  // 192^-0.5 folded into Q
    const float* src = qf + (size_t)t * N2 + h * 192;
    ushort* dst = qb + ((size_t)h * S + t) * 192;
    if (p < 64) {
        dst[2 * p]     = f2b(src[2 * p] * sc);
        dst[2 * p + 1] = f2b(src[2 * p + 1] * sc);
    } else {
        int j = p - 64;
        float c = cosb[t * 32 + j], s = sinb[t * 32 + j];
        float xr = src[128 + 2 * j], xi = src[128 + 2 * j + 1];
        dst[128 + 2 * j]     = f2b((xr * c - xi * s) * sc);
        dst[128 + 2 * j + 1] = f2b((xr * s + xi * c) * sc);
    }
}

// ============ rope k_pe: C1 cols [2048,2112) -> kpe[S,64] f32 ================
__global__ void rope_kpe_kernel(const float* __restrict__ kvf, float* __restrict__ kpe,
                                const float* __restrict__ cosb, const float* __restrict__ sinb) {
    int idx = blockIdx.x * 256 + threadIdx.x;  // S*32
    int j = idx & 31, t = idx >> 5;
    float c = cosb[t * 32 + j], s = sinb[t * 32 + j];
    const float* p = kvf + (size_t)t * N1 + 2 * j;   // kvf pre-offset to col 2048
    float xr = p[0], xi = p[1];
    kpe[t * 64 + 2 * j] = xr * c - xi * s;
    kpe[t * 64 + 2 * j + 1] = xr * s + xi * c;
}

// ============ pack kvexp_h + kpe -> kb[NH][S][192], vT[NH][128][S] ===========
__global__ __launch_bounds__(256) void pack_kv(const ushort* __restrict__ kvexp_h,
                                               const float* __restrict__ kpe,
                                               ushort* __restrict__ kb,
                                               ushort* __restrict__ vT) {
    __shared__ ushort t[64][136];
    const int s0 = blockIdx.x * 64, h = blockIdx.y, tid = threadIdx.x;
    const int row = tid >> 2, c = tid & 3;
    const ushort* src = kvexp_h + (size_t)(s0 + row) * 4096 + h * 256;
    ushort* kbr = kb + ((size_t)h * S + s0 + row) * 192;
#pragma unroll
    for (int i = 0; i < 4; i++) {
        int off = c * 32 + i * 8;
        *(uint4*)(kbr + off) = *(const uint4*)(src + off);        // K nope part
        *(uint4*)(&t[row][off]) = *(const uint4*)(src + 128 + off); // V part -> LDS
    }
    const float* kp = kpe + (size_t)(s0 + row) * 64 + c * 16;
#pragma unroll
    for (int i = 0; i < 16; i++) kbr[128 + c * 16 + i] = f2b(kp[i]);
    __syncthreads();
    const int d = tid >> 1, sh = (tid & 1) * 32;
    ushort* dst = vT + ((size_t)h * 128 + d) * S + s0 + sh;
#pragma unroll
    for (int i = 0; i < 32; i++) dst[i] = t[sh + i][d];
}

// ============ rope non-interleaved on qi first 64 dims (strided) =============
__global__ void rope_qi_kernel(float* __restrict__ qi, const float* __restrict__ cosb,
                               const float* __restrict__ sinb) {
    int idx = blockIdx.x * 256 + threadIdx.x;  // S*4*32
    int j = idx & 31, h = (idx >> 5) & 3, t = idx >> 7;
    float c = cosb[t * 32 + j], s = sinb[t * 32 + j];
    float* p = qi + (size_t)t * N2 + h * ID;   // qi pre-offset to col 3072
    float x1 = p[j], x2 = p[j + 32];
    p[j] = x1 * c - x2 * s;
    p[j + 32] = x1 * s + x2 * c;
}

// ============ layernorm + rope on ki rows (strided, in C1) ===================
__global__ __launch_bounds__(128) void ki_ln_rope_kernel(float* __restrict__ ki,
                                                         const float* __restrict__ g,
                                                         const float* __restrict__ bb,
                                                         const float* __restrict__ cosb,
                                                         const float* __restrict__ sinb) {
    int t = blockIdx.x, tid = threadIdx.x;
    float* p = ki + (size_t)t * N1;            // ki pre-offset to col 2112
    __shared__ float s1[128], s2m[128];
    float v = p[tid];
    s1[tid] = v; s2m[tid] = v * v; __syncthreads();
    for (int st = 64; st > 0; st >>= 1) {
        if (tid < st) { s1[tid] += s1[tid + st]; s2m[tid] += s2m[tid + st]; }
        __syncthreads();
    }
    float mu = s1[0] / 128.f;
    float var = s2m[0] / 128.f - mu * mu;
    float y = (v - mu) * rsqrtf(var + 1e-6f) * g[tid] + bb[tid];
    __syncthreads();
    s1[tid] = y; __syncthreads();
    if (tid >= 64) {
        p[tid] = y;
    } else if (tid < 32) {
        float c = cosb[t * 32 + tid], s = sinb[t * 32 + tid];
        float x1 = s1[tid], x2 = s1[tid + 32];
        p[tid] = x1 * c - x2 * s;
        p[tid + 32] = x1 * s + x2 * c;
    }
}

// ============ transpose ki (strided in C1) [S,128] -> kiT [128,S] ============
__global__ void transpose_ki_kernel(const float* __restrict__ ki, float* __restrict__ kiT) {
    int idx = blockIdx.x * 256 + threadIdx.x;  // S*128
    int t = idx >> 7, d = idx & 127;
    kiT[(size_t)d * S + t] = ki[(size_t)t * N1 + d];
}

// ============ indexer score (fp32, 4 cols/thread, causal region only) ========
__global__ __launch_bounds__(256) void iscore4(const float* __restrict__ qi,
                                               const float* __restrict__ kiT,
                                               const float* __restrict__ iw,
                                               float* __restrict__ iscore) {
    int t = blockIdx.x;
    int s0 = blockIdx.y * 1024;
    if (s0 > t) return;
    int s = s0 + threadIdx.x * 4;
    __shared__ float qs[4 * ID];
    __shared__ float ws4[4];
    for (int i = threadIdx.x; i < 4 * ID; i += 256) qs[i] = qi[(size_t)t * N2 + i];
    if (threadIdx.x < 4) ws4[threadIdx.x] = iw[(size_t)t * N1 + threadIdx.x] * 0.04419417382415922f;
    __syncthreads();
    if (s > t) return;
    float a[4][4];
#pragma unroll
    for (int h = 0; h < 4; h++)
#pragma unroll
        for (int c = 0; c < 4; c++) a[h][c] = 0.f;
    for (int d = 0; d < ID; d++) {
        float4 kv = *(const float4*)(kiT + (size_t)d * S + s);
#pragma unroll
        for (int h = 0; h < 4; h++) {
            float qv = qs[h * ID + d];
            a[h][0] += qv * kv.x; a[h][1] += qv * kv.y;
            a[h][2] += qv * kv.z; a[h][3] += qv * kv.w;
        }
    }
#pragma unroll
    for (int c = 0; c < 4; c++) {
        if (s + c > t) break;
        float sc = fmaxf(a[0][c], 0.f) * ws4[0] + fmaxf(a[1][c], 0.f) * ws4[1] +
                   fmaxf(a[2][c], 0.f) * ws4[2] + fmaxf(a[3][c], 0.f) * ws4[3];
        iscore[(size_t)t * S + s + c] = sc;
    }
}

// ============ exact top-k -> bitmask (registers-resident radix select) =======
__device__ inline unsigned sortable_u32(float f) {
    unsigned u = __float_as_uint(f);
    return (u & 0x80000000u) ? ~u : (u | 0x80000000u);
}

__global__ __launch_bounds__(256) void topk_mask(const float* __restrict__ iscore,
                                                 uint32_t* __restrict__ msk) {
    int t = blockIdx.x, tid = threadIdx.x;
    uint32_t* mrow = msk + (size_t)t * 64;
    if (t < TOPK) {
        if (tid < 64) {
            int full = (t + 1) >> 5;
            uint32_t wv2 = (tid < full) ? 0xFFFFFFFFu : 0u;
            if (tid == full) { int rem = (t + 1) & 31; wv2 = rem ? ((1u << rem) - 1u) : 0u; }
            mrow[tid] = wv2;
        }
        return;
    }
    const float* row = iscore + (size_t)t * S;
    const int n = t + 1;
    const int wv = tid >> 6;
    __shared__ int hist[4][256];
    __shared__ int scan[256];
    __shared__ int bsel, ksel;
    __shared__ uint32_t bytes[256];

    int jb = tid * 8;
    float4 v0 = *(const float4*)(row + jb);
    float4 v1 = *(const float4*)(row + jb + 4);
    uint32_t lsu[8];
    {
        float vvv[8] = {v0.x, v0.y, v0.z, v0.w, v1.x, v1.y, v1.z, v1.w};
#pragma unroll
        for (int i = 0; i < 8; i++)
            lsu[i] = (jb + i < n) ? sortable_u32(vvv[i]) : 0u;
    }
    unsigned prefix = 0, prefmask = 0;
    int k = TOPK;
    for (int pass = 0; pass < 4; pass++) {
        int shift = 24 - pass * 8;
#pragma unroll
        for (int r = 0; r < 4; r++) hist[r][tid] = 0;
        __syncthreads();
#pragma unroll
        for (int i = 0; i < 8; i++) {
            uint32_t u = lsu[i];
            if ((u & prefmask) == prefix) atomicAdd(&hist[wv][(u >> shift) & 255], 1);
        }
        __syncthreads();
        int h = hist[0][tid] + hist[1][tid] + hist[2][tid] + hist[3][tid];
        scan[tid] = h; __syncthreads();
        for (int st = 1; st < 256; st <<= 1) {
            int a = scan[tid];
            int b = (tid + st < 256) ? scan[tid + st] : 0;
            __syncthreads();
            scan[tid] = a + b;
            __syncthreads();
        }
        int snext = (tid < 255) ? scan[tid + 1] : 0;
        if (scan[tid] >= k && snext < k) { bsel = tid; ksel = k - snext; }
        __syncthreads();
        prefix |= ((unsigned)bsel) << shift;
        prefmask |= 0xFFu << shift;
        k = ksel;
        __syncthreads();
    }
    const unsigned u_thr = prefix;
    const int need = k;
    uint32_t gtbits = 0, eqbits = 0;
    int eqcnt = 0;
#pragma unroll
    for (int i = 0; i < 8; i++) {
        uint32_t u = lsu[i];
        if (u > u_thr) gtbits |= 1u << i;
        else if (u == u_thr) { eqbits |= 1u << i; eqcnt++; }
    }
    scan[tid] = eqcnt; __syncthreads();
    for (int st = 1; st < 256; st <<= 1) {
        int a = scan[tid];
        int b = (tid >= st) ? scan[tid - st] : 0;
        __syncthreads();
        scan[tid] = a + b;
        __syncthreads();
    }
    int room = need - (scan[tid] - eqcnt);
    uint32_t keep = 0;
#pragma unroll
    for (int i = 0; i < 8; i++)
        if ((eqbits >> i) & 1u) { if (room > 0) { keep |= 1u << i; room--; } }
    bytes[tid] = gtbits | keep;
    __syncthreads();
    if (tid < 64)
        mrow[tid] = bytes[tid * 4] | (bytes[tid * 4 + 1] << 8) |
                    (bytes[tid * 4 + 2] << 16) | (bytes[tid * 4 + 3] << 24);
}

// ============ split-K flash attention v4: DMA staging, conflict-free layouts =
// Same 512-block decode as v3 (head->XCD affinity, pair + 2-way split-K).
// Ks[6][64][32], Vs[2][128][32]: global_load_lds DMA; frag reads 64B lane
// stride -> all 32 banks covered.
__global__ __launch_bounds__(256, 2) void fattn4(const ushort* __restrict__ qb,
                                                 const ushort* __restrict__ kb,
                                                 const ushort* __restrict__ vT,
                                                 const uint32_t* __restrict__ msk,
                                                 float* __restrict__ Opart,
                                                 float* __restrict__ mlbuf) {
    __shared__ ushort Ks[6 * 64 * 32];
    __shared__ ushort Vs[2 * 128 * 32];
    __shared__ ushort Pm[4][16 * 72];
    const int tid = threadIdx.x;
    const int w = tid >> 6, l = tid & 63, quad = l >> 4, lane = l & 15;
    const int b = blockIdx.x;
    const int r8 = b & 7, j = b >> 3;
    const int h = r8 + 8 * (j & 1);
    const int idx = j >> 1;
    const int pair = idx & 15, part = idx >> 4;
    const int ta = pair, tb = 31 - pair, nA = ta + 1;
    const int vlo = part ? 17 : 0, vhi = part ? 33 : 17;
    const int qa0 = ta * 64, qb0 = tb * 64;

    bf16x8 qfa[6], qfb[6];
    {
        const ushort* qpa = qb + ((size_t)h * S + qa0 + w * 16 + lane) * 192;
        const ushort* qpb = qb + ((size_t)h * S + qb0 + w * 16 + lane) * 192;
#pragma unroll
        for (int ks = 0; ks < 6; ks++) {
            qfa[ks] = *(const bf16x8*)(qpa + ks * 32 + quad * 8);
            qfb[ks] = *(const bf16x8*)(qpb + ks * 32 + quad * 8);
        }
    }
    f32x4 oa[8], ob[8];
#pragma unroll
    for (int i = 0; i < 8; i++) { oa[i] = (f32x4)0.f; ob[i] = (f32x4)0.f; }
    float ma[4], la[4], mb[4], lb[4];
#pragma unroll
    for (int r = 0; r < 4; r++) { ma[r] = -1e30f; la[r] = 0.f; mb[r] = -1e30f; lb[r] = 0.f; }

    ushort* pw = &Pm[w][0];
    const ushort* kbase = kb + (size_t)h * S * 192;
    const ushort* vbase = vT + (size_t)h * 128 * S;

    for (int kt = 0; kt <= tb; kt++) {
        const int idxB = (kt <= ta) ? 2 * kt : kt + nA;
        const int hasA = (kt <= ta);
        const int idxA = 2 * kt + 1;
        const bool doB = (idxB >= vlo && idxB < vhi);
        const bool doA = hasA && (idxA >= vlo && idxA < vhi);
        if (!(doA || doB)) continue;           // block-uniform
        const int s0 = kt * 64;
        __syncthreads();
        // ---- DMA stage K tile: 24 issues (6/wave). issue i: j=i>>2, rb=(i&3)*16
#pragma unroll
        for (int ii = 0; ii < 6; ii++) {
            const int i = w * 6 + ii;
            const int jk = i >> 2, rb = (i & 3) << 4;
            const ushort* src = kbase + (size_t)(s0 + rb + (l >> 2)) * 192 + jk * 32 + (l & 3) * 8;
            GLL16(src, Ks + jk * 2048 + rb * 32 + l * 8);
        }
        // ---- DMA stage V^T tile: 16 issues (4/wave). issue i: j2=i>>3, db=(i&7)*16
#pragma unroll
        for (int ii = 0; ii < 4; ii++) {
            const int i = w * 4 + ii;
            const int j2 = i >> 3, db = (i & 7) << 4;
            const ushort* src = vbase + (size_t)(db + (l >> 2)) * S + s0 + j2 * 32 + (l & 3) * 8;
            GLL16(src, Vs + j2 * 4096 + db * 32 + l * 8);
        }
        __syncthreads();   // drains DMA (vmcnt(0) before barrier)

#pragma unroll
        for (int pass = 0; pass < 2; pass++) {
            if (pass == 0 && !doA) continue;
            if (pass == 1 && !doB) continue;
            const bf16x8* qf = (pass == 0) ? qfa : qfb;
            f32x4* oacc      = (pass == 0) ? oa : ob;
            float* mm        = (pass == 0) ? ma : mb;
            float* ll        = (pass == 0) ? la : lb;
            const int q0t    = (pass == 0) ? qa0 : qb0;

            // QK^T
            f32x4 sc[4];
#pragma unroll
            for (int kq = 0; kq < 4; kq++) {
                sc[kq] = (f32x4)0.f;
#pragma unroll
                for (int ks = 0; ks < 6; ks++) {
                    bf16x8 bfr = *(const bf16x8*)(Ks + ks * 2048 + (kq * 16 + lane) * 32 + quad * 8);
                    sc[kq] = __builtin_amdgcn_mfma_f32_16x16x32_bf16(qf[ks], bfr, sc[kq], 0, 0, 0);
                }
            }
            // mask words
            uint32_t w0[4], w1[4];
            {
                const int rowbase = q0t + w * 16 + quad * 4;
#pragma unroll
                for (int r = 0; r < 4; r++) {
                    const uint32_t* mp = msk + (size_t)(rowbase + r) * 64 + (s0 >> 5);
                    w0[r] = mp[0]; w1[r] = mp[1];
                }
            }
            float vmax[4] = {-1e30f, -1e30f, -1e30f, -1e30f};
#pragma unroll
            for (int kq = 0; kq < 4; kq++) {
                const int sh = (kq & 1) * 16 + lane;
#pragma unroll
                for (int r = 0; r < 4; r++) {
                    uint32_t word = (kq < 2) ? w0[r] : w1[r];
                    float v = ((word >> sh) & 1u) ? sc[kq][r] : -1e30f;
                    sc[kq][r] = v;
                    vmax[r] = fmaxf(vmax[r], v);
                }
            }
#pragma unroll
            for (int off = 1; off < 16; off <<= 1)
#pragma unroll
                for (int r = 0; r < 4; r++)
                    vmax[r] = fmaxf(vmax[r], __shfl_xor(vmax[r], off, 64));
            float alpha[4], psum[4];
#pragma unroll
            for (int r = 0; r < 4; r++) {
                float mnew = fmaxf(mm[r], vmax[r]);
                alpha[r] = __expf(mm[r] - mnew);
                mm[r] = mnew;
                psum[r] = 0.f;
            }
#pragma unroll
            for (int kq = 0; kq < 4; kq++)
#pragma unroll
                for (int r = 0; r < 4; r++) {
                    float v = sc[kq][r];
                    float e = (v < -1e29f) ? 0.f : __expf(v - mm[r]);
                    psum[r] += e;
                    pw[(quad * 4 + r) * 72 + kq * 16 + lane] = f2b(e);
                }
#pragma unroll
            for (int off = 1; off < 16; off <<= 1)
#pragma unroll
                for (int r = 0; r < 4; r++)
                    psum[r] += __shfl_xor(psum[r], off, 64);
#pragma unroll
            for (int r = 0; r < 4; r++) ll[r] = ll[r] * alpha[r] + psum[r];

            bf16x8 pfr[2];
#pragma unroll
            for (int k2 = 0; k2 < 2; k2++)
                pfr[k2] = *(const bf16x8*)(pw + lane * 72 + k2 * 32 + quad * 8);
#pragma unroll
            for (int nt = 0; nt < 8; nt++) {
#pragma unroll
                for (int r = 0; r < 4; r++) oacc[nt][r] *= alpha[r];
#pragma unroll
                for (int k2 = 0; k2 < 2; k2++) {
                    bf16x8 vfr = *(const bf16x8*)(Vs + k2 * 4096 + (nt * 16 + lane) * 32 + quad * 8);
                    oacc[nt] = __builtin_amdgcn_mfma_f32_16x16x32_bf16(pfr[k2], vfr, oacc[nt], 0, 0, 0);
                }
            }
        }
    }
    // epilogue: write f32 partials (unnormalized O + m,l)
#pragma unroll
    for (int pass = 0; pass < 2; pass++) {
        const f32x4* oacc = (pass == 0) ? oa : ob;
        const float* mm   = (pass == 0) ? ma : mb;
        const float* ll   = (pass == 0) ? la : lb;
        const int qt      = (pass == 0) ? ta : tb;
        float* Op = Opart + (size_t)(((qt * 16 + h) * 2) + part) * (64 * 128);
        float* mlp = mlbuf + (size_t)(((qt * 16 + h) * 2) + part) * 128;
#pragma unroll
        for (int nt = 0; nt < 8; nt++)
#pragma unroll
            for (int r = 0; r < 4; r++)
                Op[(w * 16 + quad * 4 + r) * 128 + nt * 16 + lane] = oacc[nt][r];
        if (lane == 0) {
#pragma unroll
            for (int r = 0; r < 4; r++) {
                mlp[(w * 16 + quad * 4 + r) * 2 + 0] = mm[r];
                mlp[(w * 16 + quad * 4 + r) * 2 + 1] = ll[r];
            }
        }
    }
}

// ============ combine split-K partials -> attn_b bf16 ========================
__global__ __launch_bounds__(256) void attn_combine(const float* __restrict__ Opart,
                                                    const float* __restrict__ mlbuf,
                                                    ushort* __restrict__ attn_b) {
    const int qt = blockIdx.x, h = blockIdx.y, tid = threadIdx.x;
    const size_t base = ((size_t)qt * 16 + h) * 2;
    const float* Op0 = Opart + base * (64 * 128);
    const float* Op1 = Op0 + 64 * 128;
    const float* ml0 = mlbuf + base * 128;
    const float* ml1 = ml0 + 128;
#pragma unroll
    for (int i = 0; i < 32; i++) {
        int id = tid + i * 256;
        int row = id >> 7, d = id & 127;
        float m0 = ml0[row * 2], l0 = ml0[row * 2 + 1];
        float m1 = ml1[row * 2], l1 = ml1[row * 2 + 1];
        float m = fmaxf(m0, m1);
        float e0 = __expf(m0 - m), e1 = __expf(m1 - m);
        float linv = 1.f / (l0 * e0 + l1 * e1);
        float v = (Op0[id] * e0 + Op1[id] * e1) * linv;
        attn_b[(size_t)(qt * 64 + row) * 2048 + h * 128 + d] = f2b(v);
    }
}

// ============ host ===========================================================
extern "C" void kernel_launch(void* const* d_in, const int* in_sizes, int n_in,
                              void* d_out, int out_size, void* d_ws, size_t ws_size,
                              hipStream_t stream) {
    const float* x        = (const float*)d_in[0];
    const float* cosb     = (const float*)d_in[1];
    const float* sinb     = (const float*)d_in[2];
    const float* Wq_a     = (const float*)d_in[4];
    const float* q_norm_w = (const float*)d_in[5];
    const float* Wq_b     = (const float*)d_in[6];
    const float* Wkv_a    = (const float*)d_in[7];
    const float* kv_norm_w= (const float*)d_in[8];
    const float* Wkv_b    = (const float*)d_in[9];
    const float* Wo       = (const float*)d_in[10];
    const float* IWq_b    = (const float*)d_in[11];
    const float* IWk      = (const float*)d_in[12];
    const float* Ik_norm_w= (const float*)d_in[13];
    const float* Ik_norm_b= (const float*)d_in[14];
    const float* IWproj   = (const float*)d_in[15];
    float* out = (float*)d_out;

    char* ws = (char*)d_ws;
    size_t o = 0;
    auto take = [&](size_t b) { char* p = ws + o; o += (b + 255) & ~(size_t)255; return p; };
    ushort* xb     = (ushort*)take((size_t)S * HID * 2);
    ushort* qrb    = (ushort*)take((size_t)S * QL * 2);
    ushort* qb     = (ushort*)take((size_t)NH * S * DQ * 2);
    ushort* kvnb   = (ushort*)take((size_t)S * KVL * 2);
    float*  kpe    = (float*)take((size_t)S * DR * 4);
    ushort* kb     = (ushort*)take((size_t)NH * S * DQ * 2);
    ushort* vT     = (ushort*)take((size_t)NH * DV * S * 2);
    uint32_t* msk  = (uint32_t*)take((size_t)S * 64 * 4);
    float*  mlbuf  = (float*)take((size_t)32 * 16 * 2 * 64 * 2 * 4);
    ushort* WTp    = (ushort*)take((size_t)N2 * QL * 2);            // 11 MB, reused serially
    float*  C1     = (float*)take((size_t)S * N1 * 4);              // 18.4 MB
    char*   big    = take((size_t)S * 4096 * 4 + 1024);             // 33.6 MB: C2 then Opart
    ushort* kvexp_h= (ushort*)take((size_t)S * 4096 * 2);           // 16.8 MB
    float*  kiT    = (float*)take((size_t)128 * S * 4);
    char*   poolb  = take((size_t)16777216);                        // iscore / attn_b

    float* C2     = (float*)big;              // [S][N2]
    float* Opart  = (float*)big;              // after iscore consumed C2's qi
    float* iscore = (float*)poolb;
    ushort* attn_b = (ushort*)poolb;          // after topk consumed iscore

    // --- x -> bf16
    cvt_bf16<<<(S * HID) / 1024, 256, 0, stream>>>(x, xb);

    // --- concatenated x-GEMM: [Wq_a | Wkv_a | IWk | IWproj] -> C1 [S,2244]
    wtrans<<<dim3(32, 24), 256, 0, stream>>>(Wq_a, WTp, HID, QL);
    wtrans<<<dim3(32, 9),  256, 0, stream>>>(Wkv_a, WTp + (size_t)1536 * HID, HID, KVL + DR);
    wtrans<<<dim3(32, 2),  256, 0, stream>>>(IWk, WTp + (size_t)2112 * HID, HID, ID);
    wtrans<<<dim3(32, 1),  256, 0, stream>>>(IWproj, WTp + (size_t)2240 * HID, HID, IH);
    gemm_bt<<<dim3(CDIV(N1, 128), S / 128), 256, 0, stream>>>(xb, WTp, C1, S, N1, HID);

    rmsnorm_b<<<S, 256, 0, stream>>>(C1, N1, qrb, QL, q_norm_w, QL);
    rmsnorm_b<<<S, 256, 0, stream>>>(C1 + 1536, N1, kvnb, KVL, kv_norm_w, KVL);
    rope_kpe_kernel<<<(S * 32) / 256, 256, 0, stream>>>(C1 + 2048, kpe, cosb, sinb);
    ki_ln_rope_kernel<<<S, 128, 0, stream>>>(C1 + 2112, Ik_norm_w, Ik_norm_b, cosb, sinb);
    transpose_ki_kernel<<<(S * ID) / 256, 256, 0, stream>>>(C1 + 2112, kiT);

    // --- concatenated qr-GEMM: [Wq_b | IWq_b] -> C2 [S,3584]
    wtrans<<<dim3(24, 48), 256, 0, stream>>>(Wq_b, WTp, QL, NH * DQ);
    wtrans<<<dim3(24, 8),  256, 0, stream>>>(IWq_b, WTp + (size_t)3072 * QL, QL, IH * ID);
    gemm_bt<<<dim3(N2 / 128, S / 128), 256, 0, stream>>>(qrb, WTp, C2, S, N2, QL);
    rope_q_b<<<(S * NH * 96) / 256, 256, 0, stream>>>(C2, qb, cosb, sinb);
    rope_qi_kernel<<<(S * IH * 32) / 256, 256, 0, stream>>>(C2 + 3072, cosb, sinb);

    // --- kv_exp = kvn @ Wkv_b (bf16 out) ; pack kb / vT
    wtrans<<<dim3(8, 64), 256, 0, stream>>>(Wkv_b, WTp, KVL, NH * (DN + DV));
    gemm_bt_h<<<dim3(32, S / 128), 256, 0, stream>>>(kvnb, WTp, kvexp_h, S, NH * (DN + DV), KVL);
    pack_kv<<<dim3(S / 64, NH), 256, 0, stream>>>(kvexp_h, kpe, kb, vT);

    // --- indexer scores + exact top-k -> bitmap
    iscore4<<<dim3(S, S / 1024), 256, 0, stream>>>(C2 + 3072, kiT, C1 + 2240, iscore);
    topk_mask<<<S, 256, 0, stream>>>(iscore, msk);

    // --- split-K masked flash attention + combine
    fattn4<<<512, 256, 0, stream>>>(qb, kb, vT, msk, Opart, mlbuf);
    attn_combine<<<dim3(32, 16), 256, 0, stream>>>(Opart, mlbuf, attn_b);

    // --- out = attn @ Wo
    wtrans<<<dim3(32, 32), 256, 0, stream>>>(Wo, WTp, NH * DV, HID);
    gemm_bt<<<dim3(HID / 128, S / 128), 256, 0, stream>>>(attn_b, WTp, out, S, HID, NH * DV);

    (void)in_sizes; (void)n_in; (void)out_size; (void)ws_size; (void)o;
}